// Round 5
// baseline (6855.537 us; speedup 1.0000x reference)
//
#include <hip/hip_runtime.h>
#include <hip/hip_bf16.h>

// PointDSC-like network. B=2, N=3000, C=128, H=1, L=6. FP32 I/O.
// Round 5 (bisection): round-4 plumbing (conv_qkv hi/lo f16, K-split, combine,
// MSG [B,N,C]) + round-2's known-good VALU attention core (fp32 = hi+lo).
// PASS => bug was in the MFMA core. FAIL => bug is in plumbing.

#define BB 2
#define NN 3000
#define CC 128
#define LAYERS 6
#define BN_EPS 1e-5f
#define ATT_SCALE 0.08838834764831845f  // 1/sqrt(128)

typedef _Float16 f16;

// ---------------- init embedding: x[b,c,n] = sum_d W[c,d]*corr[b,n,d] + b[c]
__global__ void init_conv(const float* __restrict__ corr, const float* __restrict__ W,
                          const float* __restrict__ bias, float* __restrict__ x) {
  int idx = blockIdx.x * 256 + threadIdx.x;
  if (idx >= BB * CC * NN) return;
  int n = idx % NN;
  int c = (idx / NN) % CC;
  int b = idx / (NN * CC);
  const float* cp = corr + (b * NN + n) * 6;
  float acc = bias[c];
#pragma unroll
  for (int d = 0; d < 6; ++d) acc += W[c * 6 + d] * cp[d];
  x[idx] = acc;
}

// ---------------- generic pointwise conv
// MODE: 0 plain fp32 [B,C,N]; 1 relu fp32; 2 residual fp32.
// INPT: 0 input fp32 [B,C,N]; 1 input fp32 [B,N,C].
// CSPLIT: blockIdx.y splits COUT into CSPLIT groups.
template <int CIN, int COUT, int MODE, int INPT, int CSPLIT>
__launch_bounds__(256)
__global__ void conv_k(const float* __restrict__ in, float* __restrict__ out,
                       const float* __restrict__ W, const float* __restrict__ bias,
                       const float* __restrict__ res) {
  constexpr int COB = COUT / CSPLIT;
  constexpr int CH = (CIN > 64) ? 64 : CIN;
  constexpr int KPT = COB / 32;
  __shared__ alignas(16) float Xs[CIN][INPT ? 36 : 32];
  __shared__ float Ws[COB][CH + 1];
  const int tid = threadIdx.x;
  const int p0 = blockIdx.x * 32;
  const int co0 = blockIdx.y * COB;

  if (INPT == 0) {
    for (int idx = tid; idx < CIN * 32; idx += 256) {
      int ci = idx >> 5, j = idx & 31;
      int p = p0 + j;
      float v = 0.f;
      if (p < BB * NN) {
        int b = p / NN, n = p % NN;
        v = in[(b * CIN + ci) * NN + n];
      }
      Xs[ci][j] = v;
    }
  } else {
    for (int idx = tid; idx < CIN * 32; idx += 256) {
      int j = idx / CIN, ci = idx % CIN;
      int p = p0 + j;
      float v = 0.f;
      if (p < BB * NN) v = in[p * CIN + ci];
      Xs[ci][j] = v;
    }
  }

  const int nb = (tid % 8) * 4;
  const int cb = (tid / 8) * KPT;

  float acc[KPT][4];
#pragma unroll
  for (int k = 0; k < KPT; ++k)
#pragma unroll
    for (int j = 0; j < 4; ++j) acc[k][j] = 0.f;

  for (int c0 = 0; c0 < CIN; c0 += CH) {
    __syncthreads();
    for (int idx = tid; idx < COB * CH; idx += 256) {
      int co = idx / CH, cc = idx % CH;
      Ws[co][cc] = W[(co0 + co) * CIN + c0 + cc];
    }
    __syncthreads();
#pragma unroll 4
    for (int cc = 0; cc < CH; ++cc) {
      float4 xv = *reinterpret_cast<const float4*>(&Xs[c0 + cc][nb]);
#pragma unroll
      for (int k = 0; k < KPT; ++k) {
        float w = Ws[cb + k][cc];
        acc[k][0] += w * xv.x;
        acc[k][1] += w * xv.y;
        acc[k][2] += w * xv.z;
        acc[k][3] += w * xv.w;
      }
    }
  }

#pragma unroll
  for (int k = 0; k < KPT; ++k) {
    float bv = bias[co0 + cb + k];
#pragma unroll
    for (int j = 0; j < 4; ++j) {
      int p = p0 + nb + j;
      if (p < BB * NN) {
        int b = p / NN, n = p % NN;
        int o = (b * COUT + co0 + cb + k) * NN + n;
        float v = acc[k][j] + bv;
        if (MODE == 1) v = v > 0.f ? v : 0.f;
        if (MODE == 2) v += res[o];
        out[o] = v;
      }
    }
  }
}

// ---------------- fused QKV conv: X fp32 [B,C,N] -> hi/lo f16 planes.
// Q,K planes [B,N,C]; V planes [B,C,N]. grid (PT, 6): sel = y>>1, co half = y&1.
__launch_bounds__(256)
__global__ void conv_qkv(const float* __restrict__ X,
                         const float* __restrict__ qW, const float* __restrict__ kW,
                         const float* __restrict__ vW, const float* __restrict__ qb,
                         const float* __restrict__ kb, const float* __restrict__ vb,
                         f16* __restrict__ Qh, f16* __restrict__ Ql,
                         f16* __restrict__ Kh, f16* __restrict__ Kl,
                         f16* __restrict__ Vh, f16* __restrict__ Vl) {
  __shared__ alignas(16) float Xs[128][32];
  __shared__ float Ws[64][65];
  const int tid = threadIdx.x;
  const int p0 = blockIdx.x * 32;
  const int sel = blockIdx.y >> 1;
  const int co0 = (blockIdx.y & 1) * 64;
  const float* W = (sel == 0) ? qW : (sel == 1) ? kW : vW;
  const float* bias = (sel == 0) ? qb : (sel == 1) ? kb : vb;

  for (int idx = tid; idx < 128 * 32; idx += 256) {
    int ci = idx >> 5, j = idx & 31;
    int p = p0 + j;
    float v = 0.f;
    if (p < BB * NN) {
      int b = p / NN, n = p % NN;
      v = X[(b * 128 + ci) * NN + n];
    }
    Xs[ci][j] = v;
  }

  const int nb = (tid % 8) * 4;
  const int cb = (tid / 8) * 2;
  float acc[2][4] = {{0.f, 0.f, 0.f, 0.f}, {0.f, 0.f, 0.f, 0.f}};

  for (int c0 = 0; c0 < 128; c0 += 64) {
    __syncthreads();
    for (int idx = tid; idx < 64 * 64; idx += 256) {
      int co = idx >> 6, cc = idx & 63;
      Ws[co][cc] = W[(co0 + co) * 128 + c0 + cc];
    }
    __syncthreads();
#pragma unroll 4
    for (int cc = 0; cc < 64; ++cc) {
      float4 xv = *reinterpret_cast<const float4*>(&Xs[c0 + cc][nb]);
#pragma unroll
      for (int k = 0; k < 2; ++k) {
        float w = Ws[cb + k][cc];
        acc[k][0] += w * xv.x;
        acc[k][1] += w * xv.y;
        acc[k][2] += w * xv.z;
        acc[k][3] += w * xv.w;
      }
    }
  }

#pragma unroll
  for (int k = 0; k < 2; ++k) {
    int co = co0 + cb + k;
    float bv = bias[co];
#pragma unroll
    for (int j = 0; j < 4; ++j) {
      int p = p0 + nb + j;
      if (p < BB * NN) {
        int b = p / NN, n = p % NN;
        float v = acc[k][j] + bv;
        f16 h = (f16)v;
        f16 lo = (f16)(v - (float)h);
        if (sel == 0) {
          size_t o = (size_t)(b * NN + n) * CC + co;
          Qh[o] = h; Ql[o] = lo;
        } else if (sel == 1) {
          size_t o = (size_t)(b * NN + n) * CC + co;
          Kh[o] = h; Kl[o] = lo;
        } else {
          size_t o = (size_t)(b * CC + co) * NN + n;
          Vh[o] = h; Vl[o] = lo;
        }
      }
    }
  }
}

// ---------------- BN batch stats + apply
template <int COUT>
__launch_bounds__(256)
__global__ void bn_stats(const float* __restrict__ y, const float* __restrict__ g,
                         const float* __restrict__ beta, float* __restrict__ ss) {
  int c = blockIdx.x;
  float s = 0.f, s2 = 0.f;
  for (int b = 0; b < BB; ++b) {
    const float* row = y + (b * COUT + c) * NN;
    for (int n = threadIdx.x; n < NN; n += 256) {
      float v = row[n];
      s += v;
      s2 += v * v;
    }
  }
  for (int off = 32; off > 0; off >>= 1) {
    s += __shfl_down(s, off);
    s2 += __shfl_down(s2, off);
  }
  __shared__ float rs[4], rs2[4];
  int wid = threadIdx.x >> 6, lane = threadIdx.x & 63;
  if (lane == 0) {
    rs[wid] = s;
    rs2[wid] = s2;
  }
  __syncthreads();
  if (threadIdx.x == 0) {
    float S = 0.f, S2 = 0.f;
    for (int w = 0; w < 4; ++w) {
      S += rs[w];
      S2 += rs2[w];
    }
    const float inv_cnt = 1.f / (float)(BB * NN);
    float mean = S * inv_cnt;
    float var = S2 * inv_cnt - mean * mean;
    float scale = g[c] * rsqrtf(var + BN_EPS);
    ss[c] = scale;
    ss[COUT + c] = beta[c] - mean * scale;
  }
}

template <int COUT>
__global__ void bn_apply(const float* __restrict__ y, const float* __restrict__ ss,
                         float* __restrict__ out) {
  int idx = blockIdx.x * 256 + threadIdx.x;
  if (idx >= BB * COUT * NN) return;
  int c = (idx / NN) % COUT;
  float v = y[idx] * ss[c] + ss[COUT + c];
  out[idx] = v > 0.f ? v : 0.f;
}

// ---------------- VALU flash attention (round-2 core) with K-split partials.
// Q,K read from hi/lo f16 [B,N,C]; V from hi/lo f16 [B,C,N]; fp32 = hi+lo.
// Block: 16 queries; iterates keys of its chunk in 16-key tiles.
__launch_bounds__(256)
__global__ void attn_valu(const f16* __restrict__ Qhp, const f16* __restrict__ Qlp,
                          const f16* __restrict__ Khp, const f16* __restrict__ Klp,
                          const f16* __restrict__ Vhp, const f16* __restrict__ Vlp,
                          const float* __restrict__ srcp, const float* __restrict__ tgtp,
                          float* __restrict__ pacc, float* __restrict__ pm,
                          float* __restrict__ pl, int chunk) {
  const int b = blockIdx.z;
  const int n0 = blockIdx.x * 16;
  const int s = blockIdx.y;
  const int cs = s * chunk;
  const int ce = min(cs + chunk, NN);
  const int tid = threadIdx.x;

  __shared__ alignas(16) float Qs[16][132], Ks[16][132], Vs[16][132];
  __shared__ float S[16][17];
  __shared__ float qp[16][6], kp[16][6];

  // stage Q (fp32 = hi+lo), [B,N,C]: consecutive tid -> consecutive channel
  for (int idx = tid; idx < 2048; idx += 256) {
    int o = idx >> 7, c = idx & 127;
    int n = n0 + o;
    float v = 0.f;
    if (n < NN) {
      size_t off = (size_t)(b * NN + n) * CC + c;
      v = (float)Qhp[off] + (float)Qlp[off];
    }
    Qs[o][c] = v;
  }
  if (tid < 96) {
    int o = tid / 6, d = tid % 6;
    int n = n0 + o;
    float v = 0.f;
    if (n < NN) v = (d < 3) ? srcp[(b * NN + n) * 3 + d] : tgtp[(b * NN + n) * 3 + d - 3];
    qp[o][d] = v;
  }

  const int o_s = tid >> 4, i_s = tid & 15;  // score-phase role
  const int o_a = tid & 15, g = tid >> 4;    // accum-phase role: 8 channels each
  float m = -1e30f, l = 0.f;
  float acc[8];
#pragma unroll
  for (int k = 0; k < 8; ++k) acc[k] = 0.f;

  const int KT = (ce - cs + 15) / 16;
  for (int kt = 0; kt < KT; ++kt) {
    const int i0 = cs + kt * 16;
    __syncthreads();  // prev accum done before restaging
    for (int idx = tid; idx < 2048; idx += 256) {
      int i = idx >> 7, c = idx & 127;
      int n = i0 + i;
      if (n >= NN) n = NN - 1;
      size_t ko = (size_t)(b * NN + n) * CC + c;
      Ks[i][c] = (float)Khp[ko] + (float)Klp[ko];
      size_t vo = (size_t)(b * CC + c) * NN + n;
      Vs[i][c] = (float)Vhp[vo] + (float)Vlp[vo];
    }
    if (tid < 96) {
      int i = tid / 6, d = tid % 6;
      int n = i0 + i;
      if (n >= NN) n = NN - 1;
      kp[i][d] = (d < 3) ? srcp[(b * NN + n) * 3 + d] : tgtp[(b * NN + n) * 3 + d - 3];
    }
    __syncthreads();

    // ---- scores: one (o,i) pair per thread
    float dot = 0.f;
#pragma unroll
    for (int c4 = 0; c4 < 32; ++c4) {
      float4 q = *reinterpret_cast<const float4*>(&Qs[o_s][c4 * 4]);
      float4 k = *reinterpret_cast<const float4*>(&Ks[i_s][c4 * 4]);
      dot += q.x * k.x + q.y * k.y + q.z * k.z + q.w * k.w;
    }
    float dx = qp[o_s][0] - kp[i_s][0];
    float dy = qp[o_s][1] - kp[i_s][1];
    float dz = qp[o_s][2] - kp[i_s][2];
    float dsrc = sqrtf(dx * dx + dy * dy + dz * dz);
    dx = qp[o_s][3] - kp[i_s][3];
    dy = qp[o_s][4] - kp[i_s][4];
    dz = qp[o_s][5] - kp[i_s][5];
    float dtgt = sqrtf(dx * dx + dy * dy + dz * dz);
    float diff = dsrc - dtgt;
    float scv = 1.f - diff * diff;
    scv = scv > 0.f ? scv : 0.f;
    float logit = scv * ATT_SCALE * dot;
    if (i0 + i_s >= ce) logit = -1e30f;
    S[o_s][i_s] = logit;
    __syncthreads();

    // ---- online softmax + PV accumulate (per row o_a; 16 copies of m,l per row)
    float tm = m;
#pragma unroll
    for (int i = 0; i < 16; ++i) tm = fmaxf(tm, S[o_a][i]);
    float alpha = __expf(m - tm);
    float p[16];
    float ps = 0.f;
#pragma unroll
    for (int i = 0; i < 16; ++i) {
      p[i] = __expf(S[o_a][i] - tm);
      ps += p[i];
    }
    l = l * alpha + ps;
    m = tm;
#pragma unroll
    for (int k = 0; k < 8; ++k) acc[k] *= alpha;
#pragma unroll
    for (int i = 0; i < 16; ++i) {
      float pv = p[i];
      float4 v0 = *reinterpret_cast<const float4*>(&Vs[i][g * 8]);
      float4 v1 = *reinterpret_cast<const float4*>(&Vs[i][g * 8 + 4]);
      acc[0] += pv * v0.x;
      acc[1] += pv * v0.y;
      acc[2] += pv * v0.z;
      acc[3] += pv * v0.w;
      acc[4] += pv * v1.x;
      acc[5] += pv * v1.y;
      acc[6] += pv * v1.z;
      acc[7] += pv * v1.w;
    }
  }

  // ---- write partials (UNNORMALIZED acc + per-row m, l)
  const int o = n0 + o_a;
  if (o < NN) {
    const int pidx = s * BB + b;
    if (g == 0) {
      pm[pidx * NN + o] = m;
      pl[pidx * NN + o] = l;
    }
    size_t base = ((size_t)pidx * NN + o) * CC + g * 8;
#pragma unroll
    for (int k = 0; k < 8; ++k) pacc[base + k] = acc[k];
  }
}

// ---------------- combine K-split partials -> msg fp32 [B,N,C]
__global__ void attn_combine(const float* __restrict__ pacc, const float* __restrict__ pm,
                             const float* __restrict__ pl, float* __restrict__ msg,
                             int ksplit) {
  int idx = blockIdx.x * 256 + threadIdx.x;
  if (idx >= BB * NN * CC) return;
  int c = idx & 127;
  int rem = idx >> 7;
  int o = rem % NN;
  int b = rem / NN;
  float M = -1e30f;
  for (int s = 0; s < ksplit; ++s) M = fmaxf(M, pm[(s * BB + b) * NN + o]);
  float L = 0.f, V = 0.f;
  for (int s = 0; s < ksplit; ++s) {
    int pi = s * BB + b;
    float e = __expf(pm[pi * NN + o] - M);
    L += pl[pi * NN + o] * e;
    V += pacc[((size_t)pi * NN + o) * CC + c] * e;
  }
  msg[idx] = V / L;
}

// ---------------- head + output
__global__ void head_c3(const float* __restrict__ h, const float* __restrict__ W,
                        const float* __restrict__ bias, float* __restrict__ out) {
  int p = blockIdx.x * 256 + threadIdx.x;
  if (p >= BB * NN) return;
  int b = p / NN, n = p % NN;
  float acc = bias[0];
#pragma unroll
  for (int k = 0; k < 32; ++k) acc += W[k] * h[(b * 32 + k) * NN + n];
  out[p] = acc;
}

__global__ void norm_out(const float* __restrict__ x, float* __restrict__ out) {
  int p = blockIdx.x * 256 + threadIdx.x;
  if (p >= BB * NN) return;
  int b = p / NN, n = p % NN;
  float ss = 0.f;
  for (int c = 0; c < CC; ++c) {
    float v = x[(b * CC + c) * NN + n];
    ss += v * v;
  }
  float nrm = sqrtf(ss);
  nrm = nrm > 1e-12f ? nrm : 1e-12f;
  float inv = 1.f / nrm;
  for (int c = 0; c < CC; ++c) {
    float v = x[(b * CC + c) * NN + n];
    out[BB * NN + (b * CC + c) * NN + n] = v * inv;
  }
}

extern "C" void kernel_launch(void* const* d_in, const int* in_sizes, int n_in,
                              void* d_out, int out_size, void* d_ws, size_t ws_size,
                              hipStream_t stream) {
  const float* corr = (const float*)d_in[0];
  const float* srcp = (const float*)d_in[1];
  const float* tgtp = (const float*)d_in[2];
  const float* initW = (const float*)d_in[3];
  const float* initb = (const float*)d_in[4];
  const float* pcnW = (const float*)d_in[5];
  const float* pcnb = (const float*)d_in[6];
  const float* pcng = (const float*)d_in[7];
  const float* pcnbeta = (const float*)d_in[8];
  const float* qW = (const float*)d_in[9];
  const float* qb = (const float*)d_in[10];
  const float* kW = (const float*)d_in[11];
  const float* kb = (const float*)d_in[12];
  const float* vW = (const float*)d_in[13];
  const float* vb = (const float*)d_in[14];
  const float* m1W = (const float*)d_in[15];
  const float* m1b = (const float*)d_in[16];
  const float* m1g = (const float*)d_in[17];
  const float* m1beta = (const float*)d_in[18];
  const float* m2W = (const float*)d_in[19];
  const float* m2b = (const float*)d_in[20];
  const float* m2g = (const float*)d_in[21];
  const float* m2beta = (const float*)d_in[22];
  const float* m3W = (const float*)d_in[23];
  const float* m3b = (const float*)d_in[24];
  const float* c1W = (const float*)d_in[25];
  const float* c1b = (const float*)d_in[26];
  const float* c2W = (const float*)d_in[27];
  const float* c2b = (const float*)d_in[28];
  const float* c3W = (const float*)d_in[29];
  const float* c3b = (const float*)d_in[30];

  const int FEAT = BB * CC * NN;   // 768000
  const int PLANE = FEAT / 2;      // one f16 plane in float units (384000)
  float* ws = (float*)d_ws;
  float* X = ws;                // [B,C,N] fp32, persistent
  float* Y = X + FEAT;          // conv temp; MSG aliases
  float* QhF = Y + FEAT;        // f16 planes (T1 aliases Qh, T2 aliases Kh)
  float* QlF = QhF + PLANE;
  float* KhF = QlF + PLANE;
  float* KlF = KhF + PLANE;
  float* VhF = KlF + PLANE;
  float* VlF = VhF + PLANE;
  float* SS = VlF + PLANE;      // 256 floats
  float* pacc = SS + 256;
  f16* Qh = (f16*)QhF;
  f16* Ql = (f16*)QlF;
  f16* Kh = (f16*)KhF;
  f16* Kl = (f16*)KlF;
  f16* Vh = (f16*)VhF;
  f16* Vl = (f16*)VlF;
  float* MSG = Y;
  float* T1 = QhF;
  float* T2 = KhF;

  // K-split sized to ws: base + ksplit*(B*N*C + 2*B*N) floats
  const size_t base_f = (size_t)(2 * FEAT + 6 * PLANE + 256);
  const size_t per_f = (size_t)BB * NN * CC + 2 * (size_t)BB * NN;
  int ksplit = 8;
  while (ksplit > 1 && (base_f + (size_t)ksplit * per_f) * 4 > ws_size) ksplit >>= 1;
  const int chunk = (((NN + ksplit - 1) / ksplit) + 7) & ~7;
  float* pm = pacc + (size_t)ksplit * BB * NN * CC;
  float* pl = pm + (size_t)ksplit * BB * NN;

  dim3 blk(256);
  const int PT = (BB * NN + 31) / 32;  // 188
  const int G_FEAT = (FEAT + 255) / 256;
  const int G_HALF = (BB * 64 * NN + 255) / 256;
  const int G_PTS = (BB * NN + 255) / 256;

  init_conv<<<G_FEAT, blk, 0, stream>>>(corr, initW, initb, X);

  for (int i = 0; i < LAYERS; ++i) {
    // PointCN: x = relu(bn(conv(x)))
    conv_k<128, 128, 0, 0, 2><<<dim3(PT, 2), blk, 0, stream>>>(
        X, Y, pcnW + i * 16384, pcnb + i * 128, nullptr);
    bn_stats<128><<<128, blk, 0, stream>>>(Y, pcng + i * 128, pcnbeta + i * 128, SS);
    bn_apply<128><<<G_FEAT, blk, 0, stream>>>(Y, SS, X);
    // QKV (hi/lo f16 planes)
    conv_qkv<<<dim3(PT, 6), blk, 0, stream>>>(X, qW + i * 16384, kW + i * 16384,
                                              vW + i * 16384, qb + i * 128, kb + i * 128,
                                              vb + i * 128, Qh, Ql, Kh, Kl, Vh, Vl);
    // VALU flash attention partials + combine -> MSG [B,N,C]
    attn_valu<<<dim3((NN + 15) / 16, ksplit, BB), blk, 0, stream>>>(
        Qh, Ql, Kh, Kl, Vh, Vl, srcp, tgtp, pacc, pm, pl, chunk);
    attn_combine<<<(FEAT + 255) / 256, blk, 0, stream>>>(pacc, pm, pl, MSG, ksplit);
    // bottleneck MLP + residual
    conv_k<128, 64, 0, 1, 1><<<dim3(PT, 1), blk, 0, stream>>>(
        MSG, T1, m1W + i * 8192, m1b + i * 64, nullptr);
    bn_stats<64><<<64, blk, 0, stream>>>(T1, m1g + i * 64, m1beta + i * 64, SS);
    bn_apply<64><<<G_HALF, blk, 0, stream>>>(T1, SS, T1);
    conv_k<64, 64, 0, 0, 1><<<dim3(PT, 1), blk, 0, stream>>>(
        T1, T2, m2W + i * 4096, m2b + i * 64, nullptr);
    bn_stats<64><<<64, blk, 0, stream>>>(T2, m2g + i * 64, m2beta + i * 64, SS);
    bn_apply<64><<<G_HALF, blk, 0, stream>>>(T2, SS, T2);
    conv_k<64, 128, 2, 0, 2><<<dim3(PT, 2), blk, 0, stream>>>(
        T2, X, m3W + i * 8192, m3b + i * 128, X);
  }

  // head
  conv_k<128, 32, 1, 0, 1><<<dim3(PT, 1), blk, 0, stream>>>(X, T1, c1W, c1b, nullptr);
  conv_k<32, 32, 1, 0, 1><<<dim3(PT, 1), blk, 0, stream>>>(T1, T2, c2W, c2b, nullptr);
  head_c3<<<G_PTS, blk, 0, stream>>>(T2, c3W, c3b, (float*)d_out);
  norm_out<<<G_PTS, blk, 0, stream>>>(X, (float*)d_out);
}

// Round 6
// 2102.062 us; speedup vs baseline: 3.2613x; 3.2613x over previous
//
#include <hip/hip_runtime.h>
#include <hip/hip_bf16.h>

// PointDSC-like network. B=2, N=3000, C=128, H=1, L=6. FP32 I/O.
// Round 6 (bisection 2): MFMA QK^T scores (hi/lo f16, 3-term) written to LDS
// via the documented D-mapping (col=lane&15, row=quad*4+reg), block barrier,
// then round-5's proven VALU softmax+PV. No Ps round-trip, no PV MFMA.

#define BB 2
#define NN 3000
#define CC 128
#define LAYERS 6
#define BN_EPS 1e-5f
#define ATT_SCALE 0.08838834764831845f  // 1/sqrt(128)

typedef _Float16 f16;
typedef _Float16 f16x8 __attribute__((ext_vector_type(8)));
typedef float f32x4 __attribute__((ext_vector_type(4)));

// ---------------- init embedding
__global__ void init_conv(const float* __restrict__ corr, const float* __restrict__ W,
                          const float* __restrict__ bias, float* __restrict__ x) {
  int idx = blockIdx.x * 256 + threadIdx.x;
  if (idx >= BB * CC * NN) return;
  int n = idx % NN;
  int c = (idx / NN) % CC;
  int b = idx / (NN * CC);
  const float* cp = corr + (b * NN + n) * 6;
  float acc = bias[c];
#pragma unroll
  for (int d = 0; d < 6; ++d) acc += W[c * 6 + d] * cp[d];
  x[idx] = acc;
}

// ---------------- generic pointwise conv (unchanged, proven)
template <int CIN, int COUT, int MODE, int INPT, int CSPLIT>
__launch_bounds__(256)
__global__ void conv_k(const float* __restrict__ in, float* __restrict__ out,
                       const float* __restrict__ W, const float* __restrict__ bias,
                       const float* __restrict__ res) {
  constexpr int COB = COUT / CSPLIT;
  constexpr int CH = (CIN > 64) ? 64 : CIN;
  constexpr int KPT = COB / 32;
  __shared__ alignas(16) float Xs[CIN][INPT ? 36 : 32];
  __shared__ float Ws[COB][CH + 1];
  const int tid = threadIdx.x;
  const int p0 = blockIdx.x * 32;
  const int co0 = blockIdx.y * COB;

  if (INPT == 0) {
    for (int idx = tid; idx < CIN * 32; idx += 256) {
      int ci = idx >> 5, j = idx & 31;
      int p = p0 + j;
      float v = 0.f;
      if (p < BB * NN) {
        int b = p / NN, n = p % NN;
        v = in[(b * CIN + ci) * NN + n];
      }
      Xs[ci][j] = v;
    }
  } else {
    for (int idx = tid; idx < CIN * 32; idx += 256) {
      int j = idx / CIN, ci = idx % CIN;
      int p = p0 + j;
      float v = 0.f;
      if (p < BB * NN) v = in[p * CIN + ci];
      Xs[ci][j] = v;
    }
  }

  const int nb = (tid % 8) * 4;
  const int cb = (tid / 8) * KPT;

  float acc[KPT][4];
#pragma unroll
  for (int k = 0; k < KPT; ++k)
#pragma unroll
    for (int j = 0; j < 4; ++j) acc[k][j] = 0.f;

  for (int c0 = 0; c0 < CIN; c0 += CH) {
    __syncthreads();
    for (int idx = tid; idx < COB * CH; idx += 256) {
      int co = idx / CH, cc = idx % CH;
      Ws[co][cc] = W[(co0 + co) * CIN + c0 + cc];
    }
    __syncthreads();
#pragma unroll 4
    for (int cc = 0; cc < CH; ++cc) {
      float4 xv = *reinterpret_cast<const float4*>(&Xs[c0 + cc][nb]);
#pragma unroll
      for (int k = 0; k < KPT; ++k) {
        float w = Ws[cb + k][cc];
        acc[k][0] += w * xv.x;
        acc[k][1] += w * xv.y;
        acc[k][2] += w * xv.z;
        acc[k][3] += w * xv.w;
      }
    }
  }

#pragma unroll
  for (int k = 0; k < KPT; ++k) {
    float bv = bias[co0 + cb + k];
#pragma unroll
    for (int j = 0; j < 4; ++j) {
      int p = p0 + nb + j;
      if (p < BB * NN) {
        int b = p / NN, n = p % NN;
        int o = (b * COUT + co0 + cb + k) * NN + n;
        float v = acc[k][j] + bv;
        if (MODE == 1) v = v > 0.f ? v : 0.f;
        if (MODE == 2) v += res[o];
        out[o] = v;
      }
    }
  }
}

// ---------------- fused QKV conv -> hi/lo f16 planes (unchanged, proven)
__launch_bounds__(256)
__global__ void conv_qkv(const float* __restrict__ X,
                         const float* __restrict__ qW, const float* __restrict__ kW,
                         const float* __restrict__ vW, const float* __restrict__ qb,
                         const float* __restrict__ kb, const float* __restrict__ vb,
                         f16* __restrict__ Qh, f16* __restrict__ Ql,
                         f16* __restrict__ Kh, f16* __restrict__ Kl,
                         f16* __restrict__ Vh, f16* __restrict__ Vl) {
  __shared__ alignas(16) float Xs[128][32];
  __shared__ float Ws[64][65];
  const int tid = threadIdx.x;
  const int p0 = blockIdx.x * 32;
  const int sel = blockIdx.y >> 1;
  const int co0 = (blockIdx.y & 1) * 64;
  const float* W = (sel == 0) ? qW : (sel == 1) ? kW : vW;
  const float* bias = (sel == 0) ? qb : (sel == 1) ? kb : vb;

  for (int idx = tid; idx < 128 * 32; idx += 256) {
    int ci = idx >> 5, j = idx & 31;
    int p = p0 + j;
    float v = 0.f;
    if (p < BB * NN) {
      int b = p / NN, n = p % NN;
      v = X[(b * 128 + ci) * NN + n];
    }
    Xs[ci][j] = v;
  }

  const int nb = (tid % 8) * 4;
  const int cb = (tid / 8) * 2;
  float acc[2][4] = {{0.f, 0.f, 0.f, 0.f}, {0.f, 0.f, 0.f, 0.f}};

  for (int c0 = 0; c0 < 128; c0 += 64) {
    __syncthreads();
    for (int idx = tid; idx < 64 * 64; idx += 256) {
      int co = idx >> 6, cc = idx & 63;
      Ws[co][cc] = W[(co0 + co) * 128 + c0 + cc];
    }
    __syncthreads();
#pragma unroll 4
    for (int cc = 0; cc < 64; ++cc) {
      float4 xv = *reinterpret_cast<const float4*>(&Xs[c0 + cc][nb]);
#pragma unroll
      for (int k = 0; k < 2; ++k) {
        float w = Ws[cb + k][cc];
        acc[k][0] += w * xv.x;
        acc[k][1] += w * xv.y;
        acc[k][2] += w * xv.z;
        acc[k][3] += w * xv.w;
      }
    }
  }

#pragma unroll
  for (int k = 0; k < 2; ++k) {
    int co = co0 + cb + k;
    float bv = bias[co];
#pragma unroll
    for (int j = 0; j < 4; ++j) {
      int p = p0 + nb + j;
      if (p < BB * NN) {
        int b = p / NN, n = p % NN;
        float v = acc[k][j] + bv;
        f16 h = (f16)v;
        f16 lo = (f16)(v - (float)h);
        if (sel == 0) {
          size_t o = (size_t)(b * NN + n) * CC + co;
          Qh[o] = h; Ql[o] = lo;
        } else if (sel == 1) {
          size_t o = (size_t)(b * NN + n) * CC + co;
          Kh[o] = h; Kl[o] = lo;
        } else {
          size_t o = (size_t)(b * CC + co) * NN + n;
          Vh[o] = h; Vl[o] = lo;
        }
      }
    }
  }
}

// ---------------- BN (unchanged, proven)
template <int COUT>
__launch_bounds__(256)
__global__ void bn_stats(const float* __restrict__ y, const float* __restrict__ g,
                         const float* __restrict__ beta, float* __restrict__ ss) {
  int c = blockIdx.x;
  float s = 0.f, s2 = 0.f;
  for (int b = 0; b < BB; ++b) {
    const float* row = y + (b * COUT + c) * NN;
    for (int n = threadIdx.x; n < NN; n += 256) {
      float v = row[n];
      s += v;
      s2 += v * v;
    }
  }
  for (int off = 32; off > 0; off >>= 1) {
    s += __shfl_down(s, off);
    s2 += __shfl_down(s2, off);
  }
  __shared__ float rs[4], rs2[4];
  int wid = threadIdx.x >> 6, lane = threadIdx.x & 63;
  if (lane == 0) {
    rs[wid] = s;
    rs2[wid] = s2;
  }
  __syncthreads();
  if (threadIdx.x == 0) {
    float S = 0.f, S2 = 0.f;
    for (int w = 0; w < 4; ++w) {
      S += rs[w];
      S2 += rs2[w];
    }
    const float inv_cnt = 1.f / (float)(BB * NN);
    float mean = S * inv_cnt;
    float var = S2 * inv_cnt - mean * mean;
    float scale = g[c] * rsqrtf(var + BN_EPS);
    ss[c] = scale;
    ss[COUT + c] = beta[c] - mean * scale;
  }
}

template <int COUT>
__global__ void bn_apply(const float* __restrict__ y, const float* __restrict__ ss,
                         float* __restrict__ out) {
  int idx = blockIdx.x * 256 + threadIdx.x;
  if (idx >= BB * COUT * NN) return;
  int c = (idx / NN) % COUT;
  float v = y[idx] * ss[c] + ss[COUT + c];
  out[idx] = v > 0.f ? v : 0.f;
}

// ---------------- hybrid attention: MFMA scores + VALU softmax/PV.
// Block: 64 queries (4 waves x 16 rows), 32-key tiles over its K-chunk.
__launch_bounds__(256)
__global__ void attn_hyb(const f16* __restrict__ Qhp, const f16* __restrict__ Qlp,
                         const f16* __restrict__ Khp, const f16* __restrict__ Klp,
                         const f16* __restrict__ Vhp, const f16* __restrict__ Vlp,
                         const float* __restrict__ srcp, const float* __restrict__ tgtp,
                         float* __restrict__ pacc, float* __restrict__ pm,
                         float* __restrict__ pl, int chunk) {
  const int b = blockIdx.z;
  const int q0 = blockIdx.x * 64;
  const int s = blockIdx.y;
  const int cs = s * chunk;
  const int ce = min(cs + chunk, NN);
  const int tid = threadIdx.x;
  const int w = tid >> 6, lane = tid & 63, quad = lane >> 4, l15 = lane & 15;

  __shared__ f16 Ksh[32][136], Ksl[32][136];      // [key][chan] f16 hi/lo (score MFMA)
  __shared__ alignas(16) float Vs[32][132];       // [key][chan] fp32 (VALU PV)
  __shared__ float Sg[4][16][36];                 // per-wave gated logits [qrow][key]
  __shared__ float kps[6][36];                    // key positions

  // q positions for the D-mapping rows (row = quad*4+r) of this wave
  float qp[4][6];
  const int orow = q0 + w * 16;
#pragma unroll
  for (int r = 0; r < 4; ++r) {
    int o = orow + quad * 4 + r;
    if (o >= NN) o = NN - 1;
#pragma unroll
    for (int d = 0; d < 3; ++d) {
      qp[r][d] = srcp[(b * NN + o) * 3 + d];
      qp[r][3 + d] = tgtp[(b * NN + o) * 3 + d];
    }
  }
  // Q fragments hi/lo: A[m=l15][k=quad*8+j], chan = cc*32 + quad*8 + j
  f16x8 qh[4], ql[4];
  {
    int o = orow + l15;
    if (o >= NN) o = NN - 1;
    size_t base = (size_t)(b * NN + o) * CC + quad * 8;
#pragma unroll
    for (int cc = 0; cc < 4; ++cc) {
      qh[cc] = *reinterpret_cast<const f16x8*>(Qhp + base + cc * 32);
      ql[cc] = *reinterpret_cast<const f16x8*>(Qlp + base + cc * 32);
    }
  }

  // VALU-phase roles (round-5 style, per wave): row o_a, channel group g*32
  const int o_a = lane & 15, g = lane >> 4;
  float m_run = -1e30f, l_run = 0.f;
  float acc[32];
#pragma unroll
  for (int k = 0; k < 32; ++k) acc[k] = 0.f;

  const int NT = (ce - cs + 31) >> 5;
  for (int it = 0; it < NT; ++it) {
    const int kk0 = cs + it * 32;
    __syncthreads();  // previous tile fully consumed (Ks/Vs/Sg)
    // stage K hi/lo [32][128] f16
    for (int t = tid; t < 1024; t += 256) {
      int plane = t >> 9, row = (t >> 4) & 31, cu = t & 15;
      int kr = kk0 + row;
      if (kr >= NN) kr = NN - 1;
      const f16* src = (plane ? Klp : Khp) + (size_t)(b * NN + kr) * CC + cu * 8;
      uint4 v = *reinterpret_cast<const uint4*>(src);
      f16* dst = plane ? &Ksl[row][cu * 8] : &Ksh[row][cu * 8];
      *reinterpret_cast<uint4*>(dst) = v;
    }
    // stage V fp32 [key][chan] (transposed; hi+lo reconstructed; clamped)
    for (int t = tid; t < 4096; t += 256) {
      int c = t >> 5, i = t & 31;
      int kr = kk0 + i;
      if (kr >= NN) kr = NN - 1;
      size_t off = (size_t)(b * CC + c) * NN + kr;
      Vs[i][c] = (float)Vhp[off] + (float)Vlp[off];
    }
    // stage key positions (clamped)
    for (int t = tid; t < 192; t += 256) {
      int d = t >> 5, i = t & 31;
      int ig = kk0 + i;
      if (ig >= NN) ig = NN - 1;
      kps[d][i] = (d < 3) ? srcp[(b * NN + ig) * 3 + d] : tgtp[(b * NN + ig) * 3 + d - 3];
    }
    __syncthreads();

    // ---- MFMA scores: 3-term hi/lo QK^T -> 16x32 per wave
    f32x4 accs[2];
#pragma unroll
    for (int k4 = 0; k4 < 2; ++k4) accs[k4] = (f32x4){0.f, 0.f, 0.f, 0.f};
#pragma unroll
    for (int cc = 0; cc < 4; ++cc) {
#pragma unroll
      for (int k4 = 0; k4 < 2; ++k4) {
        f16x8 bh = *reinterpret_cast<const f16x8*>(&Ksh[k4 * 16 + l15][cc * 32 + quad * 8]);
        f16x8 bl = *reinterpret_cast<const f16x8*>(&Ksl[k4 * 16 + l15][cc * 32 + quad * 8]);
        accs[k4] = __builtin_amdgcn_mfma_f32_16x16x32_f16(qh[cc], bl, accs[k4], 0, 0, 0);
        accs[k4] = __builtin_amdgcn_mfma_f32_16x16x32_f16(ql[cc], bh, accs[k4], 0, 0, 0);
        accs[k4] = __builtin_amdgcn_mfma_f32_16x16x32_f16(qh[cc], bh, accs[k4], 0, 0, 0);
      }
    }

    // ---- sc gate + mask via D-mapping (col=l15 -> key, row=quad*4+r -> query)
#pragma unroll
    for (int k4 = 0; k4 < 2; ++k4) {
      int iloc = k4 * 16 + l15;
      int ig = kk0 + iloc;
      float kx = kps[0][iloc], ky = kps[1][iloc], kz = kps[2][iloc];
      float tx = kps[3][iloc], ty = kps[4][iloc], tz = kps[5][iloc];
#pragma unroll
      for (int r = 0; r < 4; ++r) {
        float dx = qp[r][0] - kx, dy = qp[r][1] - ky, dz = qp[r][2] - kz;
        float dsrc = sqrtf(dx * dx + dy * dy + dz * dz);
        float ex = qp[r][3] - tx, ey = qp[r][4] - ty, ez = qp[r][5] - tz;
        float dtgt = sqrtf(ex * ex + ey * ey + ez * ez);
        float diff = dsrc - dtgt;
        float gg = 1.f - diff * diff;
        gg = gg > 0.f ? gg : 0.f;
        float val = accs[k4][r] * (ATT_SCALE * gg);
        Sg[w][quad * 4 + r][iloc] = (ig < ce) ? val : -1e30f;
      }
    }
    __syncthreads();  // Sg visible to the VALU phase

    // ---- VALU online softmax + PV (round-5 semantics, per wave)
    float tm = m_run;
#pragma unroll
    for (int i = 0; i < 32; ++i) tm = fmaxf(tm, Sg[w][o_a][i]);
    float alpha = __expf(m_run - tm);
    float p[32];
    float ps = 0.f;
#pragma unroll
    for (int i = 0; i < 32; ++i) {
      p[i] = __expf(Sg[w][o_a][i] - tm);
      ps += p[i];
    }
    l_run = l_run * alpha + ps;
    m_run = tm;
#pragma unroll
    for (int k = 0; k < 32; ++k) acc[k] *= alpha;
#pragma unroll
    for (int i = 0; i < 32; ++i) {
      float pv = p[i];
#pragma unroll
      for (int k4 = 0; k4 < 8; ++k4) {
        float4 v = *reinterpret_cast<const float4*>(&Vs[i][g * 32 + k4 * 4]);
        acc[k4 * 4 + 0] += pv * v.x;
        acc[k4 * 4 + 1] += pv * v.y;
        acc[k4 * 4 + 2] += pv * v.z;
        acc[k4 * 4 + 3] += pv * v.w;
      }
    }
  }

  // ---- write partials (unnormalized acc + per-row m, l)
  const int o = orow + o_a;
  if (o < NN) {
    const int pidx = s * BB + b;
    if (g == 0) {
      pm[pidx * NN + o] = m_run;
      pl[pidx * NN + o] = l_run;
    }
    size_t base2 = ((size_t)pidx * NN + o) * CC + g * 32;
#pragma unroll
    for (int k = 0; k < 32; ++k) pacc[base2 + k] = acc[k];
  }
}

// ---------------- combine K-split partials -> msg fp32 [B,N,C]
__global__ void attn_combine(const float* __restrict__ pacc, const float* __restrict__ pm,
                             const float* __restrict__ pl, float* __restrict__ msg,
                             int ksplit) {
  int idx = blockIdx.x * 256 + threadIdx.x;
  if (idx >= BB * NN * CC) return;
  int c = idx & 127;
  int rem = idx >> 7;
  int o = rem % NN;
  int b = rem / NN;
  float M = -1e30f;
  for (int s = 0; s < ksplit; ++s) M = fmaxf(M, pm[(s * BB + b) * NN + o]);
  float L = 0.f, V = 0.f;
  for (int s = 0; s < ksplit; ++s) {
    int pi = s * BB + b;
    float e = __expf(pm[pi * NN + o] - M);
    L += pl[pi * NN + o] * e;
    V += pacc[((size_t)pi * NN + o) * CC + c] * e;
  }
  msg[idx] = V / L;
}

// ---------------- head + output
__global__ void head_c3(const float* __restrict__ h, const float* __restrict__ W,
                        const float* __restrict__ bias, float* __restrict__ out) {
  int p = blockIdx.x * 256 + threadIdx.x;
  if (p >= BB * NN) return;
  int b = p / NN, n = p % NN;
  float acc = bias[0];
#pragma unroll
  for (int k = 0; k < 32; ++k) acc += W[k] * h[(b * 32 + k) * NN + n];
  out[p] = acc;
}

__global__ void norm_out(const float* __restrict__ x, float* __restrict__ out) {
  int p = blockIdx.x * 256 + threadIdx.x;
  if (p >= BB * NN) return;
  int b = p / NN, n = p % NN;
  float ss = 0.f;
  for (int c = 0; c < CC; ++c) {
    float v = x[(b * CC + c) * NN + n];
    ss += v * v;
  }
  float nrm = sqrtf(ss);
  nrm = nrm > 1e-12f ? nrm : 1e-12f;
  float inv = 1.f / nrm;
  for (int c = 0; c < CC; ++c) {
    float v = x[(b * CC + c) * NN + n];
    out[BB * NN + (b * CC + c) * NN + n] = v * inv;
  }
}

extern "C" void kernel_launch(void* const* d_in, const int* in_sizes, int n_in,
                              void* d_out, int out_size, void* d_ws, size_t ws_size,
                              hipStream_t stream) {
  const float* corr = (const float*)d_in[0];
  const float* srcp = (const float*)d_in[1];
  const float* tgtp = (const float*)d_in[2];
  const float* initW = (const float*)d_in[3];
  const float* initb = (const float*)d_in[4];
  const float* pcnW = (const float*)d_in[5];
  const float* pcnb = (const float*)d_in[6];
  const float* pcng = (const float*)d_in[7];
  const float* pcnbeta = (const float*)d_in[8];
  const float* qW = (const float*)d_in[9];
  const float* qb = (const float*)d_in[10];
  const float* kW = (const float*)d_in[11];
  const float* kb = (const float*)d_in[12];
  const float* vW = (const float*)d_in[13];
  const float* vb = (const float*)d_in[14];
  const float* m1W = (const float*)d_in[15];
  const float* m1b = (const float*)d_in[16];
  const float* m1g = (const float*)d_in[17];
  const float* m1beta = (const float*)d_in[18];
  const float* m2W = (const float*)d_in[19];
  const float* m2b = (const float*)d_in[20];
  const float* m2g = (const float*)d_in[21];
  const float* m2beta = (const float*)d_in[22];
  const float* m3W = (const float*)d_in[23];
  const float* m3b = (const float*)d_in[24];
  const float* c1W = (const float*)d_in[25];
  const float* c1b = (const float*)d_in[26];
  const float* c2W = (const float*)d_in[27];
  const float* c2b = (const float*)d_in[28];
  const float* c3W = (const float*)d_in[29];
  const float* c3b = (const float*)d_in[30];

  const int FEAT = BB * CC * NN;   // 768000
  const int PLANE = FEAT / 2;      // one f16 plane in float units (384000)
  float* ws = (float*)d_ws;
  float* X = ws;
  float* Y = X + FEAT;
  float* QhF = Y + FEAT;
  float* QlF = QhF + PLANE;
  float* KhF = QlF + PLANE;
  float* KlF = KhF + PLANE;
  float* VhF = KlF + PLANE;
  float* VlF = VhF + PLANE;
  float* SS = VlF + PLANE;
  float* pacc = SS + 256;
  f16* Qh = (f16*)QhF;
  f16* Ql = (f16*)QlF;
  f16* Kh = (f16*)KhF;
  f16* Kl = (f16*)KlF;
  f16* Vh = (f16*)VhF;
  f16* Vl = (f16*)VlF;
  float* MSG = Y;
  float* T1 = QhF;
  float* T2 = KhF;

  const size_t base_f = (size_t)(2 * FEAT + 6 * PLANE + 256);
  const size_t per_f = (size_t)BB * NN * CC + 2 * (size_t)BB * NN;
  int ksplit = 8;
  while (ksplit > 1 && (base_f + (size_t)ksplit * per_f) * 4 > ws_size) ksplit >>= 1;
  const int chunk = (((NN + ksplit - 1) / ksplit) + 7) & ~7;
  float* pm = pacc + (size_t)ksplit * BB * NN * CC;
  float* pl = pm + (size_t)ksplit * BB * NN;

  dim3 blk(256);
  const int PT = (BB * NN + 31) / 32;  // 188
  const int G_FEAT = (FEAT + 255) / 256;
  const int G_HALF = (BB * 64 * NN + 255) / 256;
  const int G_PTS = (BB * NN + 255) / 256;

  init_conv<<<G_FEAT, blk, 0, stream>>>(corr, initW, initb, X);

  for (int i = 0; i < LAYERS; ++i) {
    conv_k<128, 128, 0, 0, 2><<<dim3(PT, 2), blk, 0, stream>>>(
        X, Y, pcnW + i * 16384, pcnb + i * 128, nullptr);
    bn_stats<128><<<128, blk, 0, stream>>>(Y, pcng + i * 128, pcnbeta + i * 128, SS);
    bn_apply<128><<<G_FEAT, blk, 0, stream>>>(Y, SS, X);
    conv_qkv<<<dim3(PT, 6), blk, 0, stream>>>(X, qW + i * 16384, kW + i * 16384,
                                              vW + i * 16384, qb + i * 128, kb + i * 128,
                                              vb + i * 128, Qh, Ql, Kh, Kl, Vh, Vl);
    attn_hyb<<<dim3((NN + 63) / 64, ksplit, BB), blk, 0, stream>>>(
        Qh, Ql, Kh, Kl, Vh, Vl, srcp, tgtp, pacc, pm, pl, chunk);
    attn_combine<<<(FEAT + 255) / 256, blk, 0, stream>>>(pacc, pm, pl, MSG, ksplit);
    conv_k<128, 64, 0, 1, 1><<<dim3(PT, 1), blk, 0, stream>>>(
        MSG, T1, m1W + i * 8192, m1b + i * 64, nullptr);
    bn_stats<64><<<64, blk, 0, stream>>>(T1, m1g + i * 64, m1beta + i * 64, SS);
    bn_apply<64><<<G_HALF, blk, 0, stream>>>(T1, SS, T1);
    conv_k<64, 64, 0, 0, 1><<<dim3(PT, 1), blk, 0, stream>>>(
        T1, T2, m2W + i * 4096, m2b + i * 64, nullptr);
    bn_stats<64><<<64, blk, 0, stream>>>(T2, m2g + i * 64, m2beta + i * 64, SS);
    bn_apply<64><<<G_HALF, blk, 0, stream>>>(T2, SS, T2);
    conv_k<64, 128, 2, 0, 2><<<dim3(PT, 2), blk, 0, stream>>>(
        T2, X, m3W + i * 8192, m3b + i * 128, X);
  }

  conv_k<128, 32, 1, 0, 1><<<dim3(PT, 1), blk, 0, stream>>>(X, T1, c1W, c1b, nullptr);
  conv_k<32, 32, 1, 0, 1><<<dim3(PT, 1), blk, 0, stream>>>(T1, T2, c2W, c2b, nullptr);
  head_c3<<<G_PTS, blk, 0, stream>>>(T2, c3W, c3b, (float*)d_out);
  norm_out<<<G_PTS, blk, 0, stream>>>(X, (float*)d_out);
}

// Round 7
// 1943.918 us; speedup vs baseline: 3.5267x; 1.0814x over previous
//
#include <hip/hip_runtime.h>
#include <hip/hip_bf16.h>

// PointDSC-like network. B=2, N=3000, C=128, H=1, L=6. FP32 I/O.
// Round 7: full-MFMA attention. Round-6 proven scores (hi/lo f16, 3-term) +
// VALU softmax; PV now MFMA (2-term hi/lo) with the P LDS round-trip guarded
// by __syncthreads() (round-4's failure = cross-lane LDS race, no barrier).

#define BB 2
#define NN 3000
#define CC 128
#define LAYERS 6
#define BN_EPS 1e-5f
#define ATT_SCALE 0.08838834764831845f  // 1/sqrt(128)

typedef _Float16 f16;
typedef _Float16 f16x8 __attribute__((ext_vector_type(8)));
typedef float f32x4 __attribute__((ext_vector_type(4)));

// ---------------- init embedding
__global__ void init_conv(const float* __restrict__ corr, const float* __restrict__ W,
                          const float* __restrict__ bias, float* __restrict__ x) {
  int idx = blockIdx.x * 256 + threadIdx.x;
  if (idx >= BB * CC * NN) return;
  int n = idx % NN;
  int c = (idx / NN) % CC;
  int b = idx / (NN * CC);
  const float* cp = corr + (b * NN + n) * 6;
  float acc = bias[c];
#pragma unroll
  for (int d = 0; d < 6; ++d) acc += W[c * 6 + d] * cp[d];
  x[idx] = acc;
}

// ---------------- generic pointwise conv (proven)
template <int CIN, int COUT, int MODE, int INPT, int CSPLIT>
__launch_bounds__(256)
__global__ void conv_k(const float* __restrict__ in, float* __restrict__ out,
                       const float* __restrict__ W, const float* __restrict__ bias,
                       const float* __restrict__ res) {
  constexpr int COB = COUT / CSPLIT;
  constexpr int CH = (CIN > 64) ? 64 : CIN;
  constexpr int KPT = COB / 32;
  __shared__ alignas(16) float Xs[CIN][INPT ? 36 : 32];
  __shared__ float Ws[COB][CH + 1];
  const int tid = threadIdx.x;
  const int p0 = blockIdx.x * 32;
  const int co0 = blockIdx.y * COB;

  if (INPT == 0) {
    for (int idx = tid; idx < CIN * 32; idx += 256) {
      int ci = idx >> 5, j = idx & 31;
      int p = p0 + j;
      float v = 0.f;
      if (p < BB * NN) {
        int b = p / NN, n = p % NN;
        v = in[(b * CIN + ci) * NN + n];
      }
      Xs[ci][j] = v;
    }
  } else {
    for (int idx = tid; idx < CIN * 32; idx += 256) {
      int j = idx / CIN, ci = idx % CIN;
      int p = p0 + j;
      float v = 0.f;
      if (p < BB * NN) v = in[p * CIN + ci];
      Xs[ci][j] = v;
    }
  }

  const int nb = (tid % 8) * 4;
  const int cb = (tid / 8) * KPT;

  float acc[KPT][4];
#pragma unroll
  for (int k = 0; k < KPT; ++k)
#pragma unroll
    for (int j = 0; j < 4; ++j) acc[k][j] = 0.f;

  for (int c0 = 0; c0 < CIN; c0 += CH) {
    __syncthreads();
    for (int idx = tid; idx < COB * CH; idx += 256) {
      int co = idx / CH, cc = idx % CH;
      Ws[co][cc] = W[(co0 + co) * CIN + c0 + cc];
    }
    __syncthreads();
#pragma unroll 4
    for (int cc = 0; cc < CH; ++cc) {
      float4 xv = *reinterpret_cast<const float4*>(&Xs[c0 + cc][nb]);
#pragma unroll
      for (int k = 0; k < KPT; ++k) {
        float w = Ws[cb + k][cc];
        acc[k][0] += w * xv.x;
        acc[k][1] += w * xv.y;
        acc[k][2] += w * xv.z;
        acc[k][3] += w * xv.w;
      }
    }
  }

#pragma unroll
  for (int k = 0; k < KPT; ++k) {
    float bv = bias[co0 + cb + k];
#pragma unroll
    for (int j = 0; j < 4; ++j) {
      int p = p0 + nb + j;
      if (p < BB * NN) {
        int b = p / NN, n = p % NN;
        int o = (b * COUT + co0 + cb + k) * NN + n;
        float v = acc[k][j] + bv;
        if (MODE == 1) v = v > 0.f ? v : 0.f;
        if (MODE == 2) v += res[o];
        out[o] = v;
      }
    }
  }
}

// ---------------- fused QKV conv -> hi/lo f16 planes (proven)
__launch_bounds__(256)
__global__ void conv_qkv(const float* __restrict__ X,
                         const float* __restrict__ qW, const float* __restrict__ kW,
                         const float* __restrict__ vW, const float* __restrict__ qb,
                         const float* __restrict__ kb, const float* __restrict__ vb,
                         f16* __restrict__ Qh, f16* __restrict__ Ql,
                         f16* __restrict__ Kh, f16* __restrict__ Kl,
                         f16* __restrict__ Vh, f16* __restrict__ Vl) {
  __shared__ alignas(16) float Xs[128][32];
  __shared__ float Ws[64][65];
  const int tid = threadIdx.x;
  const int p0 = blockIdx.x * 32;
  const int sel = blockIdx.y >> 1;
  const int co0 = (blockIdx.y & 1) * 64;
  const float* W = (sel == 0) ? qW : (sel == 1) ? kW : vW;
  const float* bias = (sel == 0) ? qb : (sel == 1) ? kb : vb;

  for (int idx = tid; idx < 128 * 32; idx += 256) {
    int ci = idx >> 5, j = idx & 31;
    int p = p0 + j;
    float v = 0.f;
    if (p < BB * NN) {
      int b = p / NN, n = p % NN;
      v = X[(b * 128 + ci) * NN + n];
    }
    Xs[ci][j] = v;
  }

  const int nb = (tid % 8) * 4;
  const int cb = (tid / 8) * 2;
  float acc[2][4] = {{0.f, 0.f, 0.f, 0.f}, {0.f, 0.f, 0.f, 0.f}};

  for (int c0 = 0; c0 < 128; c0 += 64) {
    __syncthreads();
    for (int idx = tid; idx < 64 * 64; idx += 256) {
      int co = idx >> 6, cc = idx & 63;
      Ws[co][cc] = W[(co0 + co) * 128 + c0 + cc];
    }
    __syncthreads();
#pragma unroll 4
    for (int cc = 0; cc < 64; ++cc) {
      float4 xv = *reinterpret_cast<const float4*>(&Xs[c0 + cc][nb]);
#pragma unroll
      for (int k = 0; k < 2; ++k) {
        float w = Ws[cb + k][cc];
        acc[k][0] += w * xv.x;
        acc[k][1] += w * xv.y;
        acc[k][2] += w * xv.z;
        acc[k][3] += w * xv.w;
      }
    }
  }

#pragma unroll
  for (int k = 0; k < 2; ++k) {
    int co = co0 + cb + k;
    float bv = bias[co];
#pragma unroll
    for (int j = 0; j < 4; ++j) {
      int p = p0 + nb + j;
      if (p < BB * NN) {
        int b = p / NN, n = p % NN;
        float v = acc[k][j] + bv;
        f16 h = (f16)v;
        f16 lo = (f16)(v - (float)h);
        if (sel == 0) {
          size_t o = (size_t)(b * NN + n) * CC + co;
          Qh[o] = h; Ql[o] = lo;
        } else if (sel == 1) {
          size_t o = (size_t)(b * NN + n) * CC + co;
          Kh[o] = h; Kl[o] = lo;
        } else {
          size_t o = (size_t)(b * CC + co) * NN + n;
          Vh[o] = h; Vl[o] = lo;
        }
      }
    }
  }
}

// ---------------- BN (proven)
template <int COUT>
__launch_bounds__(256)
__global__ void bn_stats(const float* __restrict__ y, const float* __restrict__ g,
                         const float* __restrict__ beta, float* __restrict__ ss) {
  int c = blockIdx.x;
  float s = 0.f, s2 = 0.f;
  for (int b = 0; b < BB; ++b) {
    const float* row = y + (b * COUT + c) * NN;
    for (int n = threadIdx.x; n < NN; n += 256) {
      float v = row[n];
      s += v;
      s2 += v * v;
    }
  }
  for (int off = 32; off > 0; off >>= 1) {
    s += __shfl_down(s, off);
    s2 += __shfl_down(s2, off);
  }
  __shared__ float rs[4], rs2[4];
  int wid = threadIdx.x >> 6, lane = threadIdx.x & 63;
  if (lane == 0) {
    rs[wid] = s;
    rs2[wid] = s2;
  }
  __syncthreads();
  if (threadIdx.x == 0) {
    float S = 0.f, S2 = 0.f;
    for (int w = 0; w < 4; ++w) {
      S += rs[w];
      S2 += rs2[w];
    }
    const float inv_cnt = 1.f / (float)(BB * NN);
    float mean = S * inv_cnt;
    float var = S2 * inv_cnt - mean * mean;
    float scale = g[c] * rsqrtf(var + BN_EPS);
    ss[c] = scale;
    ss[COUT + c] = beta[c] - mean * scale;
  }
}

template <int COUT>
__global__ void bn_apply(const float* __restrict__ y, const float* __restrict__ ss,
                         float* __restrict__ out) {
  int idx = blockIdx.x * 256 + threadIdx.x;
  if (idx >= BB * COUT * NN) return;
  int c = (idx / NN) % COUT;
  float v = y[idx] * ss[c] + ss[COUT + c];
  out[idx] = v > 0.f ? v : 0.f;
}

// ---------------- full-MFMA attention: MFMA scores + VALU softmax + MFMA PV.
// Block: 64 queries (4 waves x 16 rows), 32-key tiles over its K-chunk.
__launch_bounds__(256)
__global__ void attn_mf2(const f16* __restrict__ Qhp, const f16* __restrict__ Qlp,
                         const f16* __restrict__ Khp, const f16* __restrict__ Klp,
                         const f16* __restrict__ Vhp, const f16* __restrict__ Vlp,
                         const float* __restrict__ srcp, const float* __restrict__ tgtp,
                         float* __restrict__ pacc, float* __restrict__ pm,
                         float* __restrict__ pl, int chunk) {
  const int b = blockIdx.z;
  const int q0 = blockIdx.x * 64;
  const int s = blockIdx.y;
  const int cs = s * chunk;
  const int ce = min(cs + chunk, NN);
  const int tid = threadIdx.x;
  const int w = tid >> 6, lane = tid & 63, quad = lane >> 4, l15 = lane & 15;

  __shared__ f16 Ksh[32][136], Ksl[32][136];  // [key][chan] hi/lo (score MFMA B)
  __shared__ f16 Vsh[128][40], Vsl[128][40];  // [chan][key] hi/lo (PV MFMA B)
  __shared__ float Sg[4][16][36];             // per-wave gated logits [qrow][key]
  __shared__ f16 Ps[4][16][40];               // per-wave P [qrow][key] (PV MFMA A)
  __shared__ float kps[6][36];                // key positions

  // q positions for D-mapping rows (row = quad*4+r) of this wave
  float qp[4][6];
  const int orow = q0 + w * 16;
#pragma unroll
  for (int r = 0; r < 4; ++r) {
    int o = orow + quad * 4 + r;
    if (o >= NN) o = NN - 1;
#pragma unroll
    for (int d = 0; d < 3; ++d) {
      qp[r][d] = srcp[(b * NN + o) * 3 + d];
      qp[r][3 + d] = tgtp[(b * NN + o) * 3 + d];
    }
  }
  // Q fragments hi/lo: A[m=l15][k=quad*8+j], chan = cc*32 + quad*8 + j
  f16x8 qh[4], ql[4];
  {
    int o = orow + l15;
    if (o >= NN) o = NN - 1;
    size_t base = (size_t)(b * NN + o) * CC + quad * 8;
#pragma unroll
    for (int cc = 0; cc < 4; ++cc) {
      qh[cc] = *reinterpret_cast<const f16x8*>(Qhp + base + cc * 32);
      ql[cc] = *reinterpret_cast<const f16x8*>(Qlp + base + cc * 32);
    }
  }

  // softmax roles (per wave): row o_a = lane&15, key-slice g = lane>>4
  const int o_a = l15, g = quad;
  float m_run = -1e30f, l_run = 0.f;
  f32x4 acco[8];  // PV accumulator, D-layout rows quad*4+r, cols t*16+l15
#pragma unroll
  for (int t = 0; t < 8; ++t) acco[t] = (f32x4){0.f, 0.f, 0.f, 0.f};

  const int NT = (ce - cs + 31) >> 5;
  for (int it = 0; it < NT; ++it) {
    const int kk0 = cs + it * 32;
    __syncthreads();  // previous tile fully consumed
    // stage K hi/lo [32][128] f16
    for (int t = tid; t < 1024; t += 256) {
      int plane = t >> 9, row = (t >> 4) & 31, cu = t & 15;
      int kr = kk0 + row;
      if (kr >= NN) kr = NN - 1;
      const f16* src = (plane ? Klp : Khp) + (size_t)(b * NN + kr) * CC + cu * 8;
      uint4 v = *reinterpret_cast<const uint4*>(src);
      f16* dst = plane ? &Ksl[row][cu * 8] : &Ksh[row][cu * 8];
      *reinterpret_cast<uint4*>(dst) = v;
    }
    // stage V hi/lo [128][32] f16 (clamped base keeps reads in-bounds;
    // out-of-range keys get p=0 so values are harmless)
    for (int t = tid; t < 1024; t += 256) {
      int plane = t >> 9, c = (t >> 2) & 127, iu = t & 3;
      int kb = kk0 + iu * 8;
      if (kb > NN - 8) kb = NN - 8;
      const f16* src = (plane ? Vlp : Vhp) + (size_t)(b * CC + c) * NN + kb;
      uint4 v = *reinterpret_cast<const uint4*>(src);
      f16* dst = plane ? &Vsl[c][iu * 8] : &Vsh[c][iu * 8];
      *reinterpret_cast<uint4*>(dst) = v;
    }
    // stage key positions (clamped)
    for (int t = tid; t < 192; t += 256) {
      int d = t >> 5, i = t & 31;
      int ig = kk0 + i;
      if (ig >= NN) ig = NN - 1;
      kps[d][i] = (d < 3) ? srcp[(b * NN + ig) * 3 + d] : tgtp[(b * NN + ig) * 3 + d - 3];
    }
    __syncthreads();

    // ---- MFMA scores: 3-term hi/lo QK^T -> 16x32 per wave
    f32x4 accs[2];
#pragma unroll
    for (int k4 = 0; k4 < 2; ++k4) accs[k4] = (f32x4){0.f, 0.f, 0.f, 0.f};
#pragma unroll
    for (int cc = 0; cc < 4; ++cc) {
#pragma unroll
      for (int k4 = 0; k4 < 2; ++k4) {
        f16x8 bh = *reinterpret_cast<const f16x8*>(&Ksh[k4 * 16 + l15][cc * 32 + quad * 8]);
        f16x8 bl = *reinterpret_cast<const f16x8*>(&Ksl[k4 * 16 + l15][cc * 32 + quad * 8]);
        accs[k4] = __builtin_amdgcn_mfma_f32_16x16x32_f16(qh[cc], bl, accs[k4], 0, 0, 0);
        accs[k4] = __builtin_amdgcn_mfma_f32_16x16x32_f16(ql[cc], bh, accs[k4], 0, 0, 0);
        accs[k4] = __builtin_amdgcn_mfma_f32_16x16x32_f16(qh[cc], bh, accs[k4], 0, 0, 0);
      }
    }

    // ---- sc gate + mask via D-mapping (col=l15 -> key, row=quad*4+r -> query)
#pragma unroll
    for (int k4 = 0; k4 < 2; ++k4) {
      int iloc = k4 * 16 + l15;
      int ig = kk0 + iloc;
      float kx = kps[0][iloc], ky = kps[1][iloc], kz = kps[2][iloc];
      float tx = kps[3][iloc], ty = kps[4][iloc], tz = kps[5][iloc];
#pragma unroll
      for (int r = 0; r < 4; ++r) {
        float dx = qp[r][0] - kx, dy = qp[r][1] - ky, dz = qp[r][2] - kz;
        float dsrc = sqrtf(dx * dx + dy * dy + dz * dz);
        float ex = qp[r][3] - tx, ey = qp[r][4] - ty, ez = qp[r][5] - tz;
        float dtgt = sqrtf(ex * ex + ey * ey + ez * ez);
        float diff = dsrc - dtgt;
        float gg = 1.f - diff * diff;
        gg = gg > 0.f ? gg : 0.f;
        float val = accs[k4][r] * (ATT_SCALE * gg);
        Sg[w][quad * 4 + r][iloc] = (ig < ce) ? val : -1e30f;
      }
    }
    __syncthreads();  // Sg visible block-wide

    // ---- VALU online softmax (per wave, row o_a; all 4 g-copies identical)
    float tm = m_run;
#pragma unroll
    for (int i = 0; i < 32; ++i) tm = fmaxf(tm, Sg[w][o_a][i]);
    float alpha = __expf(m_run - tm);
    float ps = 0.f;
    f16 pf[32];
#pragma unroll
    for (int i = 0; i < 32; ++i) {
      pf[i] = (f16)__expf(Sg[w][o_a][i] - tm);
      ps += (float)pf[i];  // sum rounded values: num/denom consistent
    }
    l_run = l_run * alpha + ps;
    m_run = tm;
    // write this g-slice of P (one b128 per lane)
    f16x8 pvw;
#pragma unroll
    for (int j = 0; j < 8; ++j) pvw[j] = pf[g * 8 + j];
    *reinterpret_cast<f16x8*>(&Ps[w][o_a][g * 8]) = pvw;

    // rescale PV accumulator rows by their alpha (fetched from softmax-role lanes)
#pragma unroll
    for (int r = 0; r < 4; ++r) {
      float ar = __shfl(alpha, (lane & 48) | (quad * 4 + r));
#pragma unroll
      for (int t = 0; t < 8; ++t) acco[t][r] *= ar;
    }
    __syncthreads();  // Ps writes complete before cross-lane A-fragment reads

    // ---- MFMA PV: A = Ps[m=l15][k=quad*8+j], B = V hi/lo (16 MFMAs)
    {
      f16x8 af = *reinterpret_cast<const f16x8*>(&Ps[w][l15][quad * 8]);
#pragma unroll
      for (int t = 0; t < 8; ++t) {
        f16x8 vh = *reinterpret_cast<const f16x8*>(&Vsh[t * 16 + l15][quad * 8]);
        f16x8 vl = *reinterpret_cast<const f16x8*>(&Vsl[t * 16 + l15][quad * 8]);
        acco[t] = __builtin_amdgcn_mfma_f32_16x16x32_f16(af, vl, acco[t], 0, 0, 0);
        acco[t] = __builtin_amdgcn_mfma_f32_16x16x32_f16(af, vh, acco[t], 0, 0, 0);
      }
    }
  }

  // ---- write partials: pm/pl by softmax roles; pacc by D-layout roles
  const int pidx = s * BB + b;
  if (g == 0 && orow + o_a < NN) {
    pm[pidx * NN + orow + o_a] = m_run;
    pl[pidx * NN + orow + o_a] = l_run;
  }
#pragma unroll
  for (int r = 0; r < 4; ++r) {
    int o = orow + quad * 4 + r;
    if (o < NN) {
      size_t base2 = ((size_t)pidx * NN + o) * CC;
#pragma unroll
      for (int t = 0; t < 8; ++t) pacc[base2 + t * 16 + l15] = acco[t][r];
    }
  }
}

// ---------------- combine K-split partials -> msg fp32 [B,N,C]
__global__ void attn_combine(const float* __restrict__ pacc, const float* __restrict__ pm,
                             const float* __restrict__ pl, float* __restrict__ msg,
                             int ksplit) {
  int idx = blockIdx.x * 256 + threadIdx.x;
  if (idx >= BB * NN * CC) return;
  int c = idx & 127;
  int rem = idx >> 7;
  int o = rem % NN;
  int b = rem / NN;
  float M = -1e30f;
  for (int s = 0; s < ksplit; ++s) M = fmaxf(M, pm[(s * BB + b) * NN + o]);
  float L = 0.f, V = 0.f;
  for (int s = 0; s < ksplit; ++s) {
    int pi = s * BB + b;
    float e = __expf(pm[pi * NN + o] - M);
    L += pl[pi * NN + o] * e;
    V += pacc[((size_t)pi * NN + o) * CC + c] * e;
  }
  msg[idx] = V / L;
}

// ---------------- head + output
__global__ void head_c3(const float* __restrict__ h, const float* __restrict__ W,
                        const float* __restrict__ bias, float* __restrict__ out) {
  int p = blockIdx.x * 256 + threadIdx.x;
  if (p >= BB * NN) return;
  int b = p / NN, n = p % NN;
  float acc = bias[0];
#pragma unroll
  for (int k = 0; k < 32; ++k) acc += W[k] * h[(b * 32 + k) * NN + n];
  out[p] = acc;
}

__global__ void norm_out(const float* __restrict__ x, float* __restrict__ out) {
  int p = blockIdx.x * 256 + threadIdx.x;
  if (p >= BB * NN) return;
  int b = p / NN, n = p % NN;
  float ss = 0.f;
  for (int c = 0; c < CC; ++c) {
    float v = x[(b * CC + c) * NN + n];
    ss += v * v;
  }
  float nrm = sqrtf(ss);
  nrm = nrm > 1e-12f ? nrm : 1e-12f;
  float inv = 1.f / nrm;
  for (int c = 0; c < CC; ++c) {
    float v = x[(b * CC + c) * NN + n];
    out[BB * NN + (b * CC + c) * NN + n] = v * inv;
  }
}

extern "C" void kernel_launch(void* const* d_in, const int* in_sizes, int n_in,
                              void* d_out, int out_size, void* d_ws, size_t ws_size,
                              hipStream_t stream) {
  const float* corr = (const float*)d_in[0];
  const float* srcp = (const float*)d_in[1];
  const float* tgtp = (const float*)d_in[2];
  const float* initW = (const float*)d_in[3];
  const float* initb = (const float*)d_in[4];
  const float* pcnW = (const float*)d_in[5];
  const float* pcnb = (const float*)d_in[6];
  const float* pcng = (const float*)d_in[7];
  const float* pcnbeta = (const float*)d_in[8];
  const float* qW = (const float*)d_in[9];
  const float* qb = (const float*)d_in[10];
  const float* kW = (const float*)d_in[11];
  const float* kb = (const float*)d_in[12];
  const float* vW = (const float*)d_in[13];
  const float* vb = (const float*)d_in[14];
  const float* m1W = (const float*)d_in[15];
  const float* m1b = (const float*)d_in[16];
  const float* m1g = (const float*)d_in[17];
  const float* m1beta = (const float*)d_in[18];
  const float* m2W = (const float*)d_in[19];
  const float* m2b = (const float*)d_in[20];
  const float* m2g = (const float*)d_in[21];
  const float* m2beta = (const float*)d_in[22];
  const float* m3W = (const float*)d_in[23];
  const float* m3b = (const float*)d_in[24];
  const float* c1W = (const float*)d_in[25];
  const float* c1b = (const float*)d_in[26];
  const float* c2W = (const float*)d_in[27];
  const float* c2b = (const float*)d_in[28];
  const float* c3W = (const float*)d_in[29];
  const float* c3b = (const float*)d_in[30];

  const int FEAT = BB * CC * NN;   // 768000
  const int PLANE = FEAT / 2;      // one f16 plane in float units (384000)
  float* ws = (float*)d_ws;
  float* X = ws;
  float* Y = X + FEAT;
  float* QhF = Y + FEAT;
  float* QlF = QhF + PLANE;
  float* KhF = QlF + PLANE;
  float* KlF = KhF + PLANE;
  float* VhF = KlF + PLANE;
  float* VlF = VhF + PLANE;
  float* SS = VlF + PLANE;
  float* pacc = SS + 256;
  f16* Qh = (f16*)QhF;
  f16* Ql = (f16*)QlF;
  f16* Kh = (f16*)KhF;
  f16* Kl = (f16*)KlF;
  f16* Vh = (f16*)VhF;
  f16* Vl = (f16*)VlF;
  float* MSG = Y;
  float* T1 = QhF;
  float* T2 = KhF;

  const size_t base_f = (size_t)(2 * FEAT + 6 * PLANE + 256);
  const size_t per_f = (size_t)BB * NN * CC + 2 * (size_t)BB * NN;
  int ksplit = 8;
  while (ksplit > 1 && (base_f + (size_t)ksplit * per_f) * 4 > ws_size) ksplit >>= 1;
  const int chunk = (((NN + ksplit - 1) / ksplit) + 7) & ~7;
  float* pm = pacc + (size_t)ksplit * BB * NN * CC;
  float* pl = pm + (size_t)ksplit * BB * NN;

  dim3 blk(256);
  const int PT = (BB * NN + 31) / 32;  // 188
  const int G_FEAT = (FEAT + 255) / 256;
  const int G_HALF = (BB * 64 * NN + 255) / 256;
  const int G_PTS = (BB * NN + 255) / 256;

  init_conv<<<G_FEAT, blk, 0, stream>>>(corr, initW, initb, X);

  for (int i = 0; i < LAYERS; ++i) {
    conv_k<128, 128, 0, 0, 2><<<dim3(PT, 2), blk, 0, stream>>>(
        X, Y, pcnW + i * 16384, pcnb + i * 128, nullptr);
    bn_stats<128><<<128, blk, 0, stream>>>(Y, pcng + i * 128, pcnbeta + i * 128, SS);
    bn_apply<128><<<G_FEAT, blk, 0, stream>>>(Y, SS, X);
    conv_qkv<<<dim3(PT, 6), blk, 0, stream>>>(X, qW + i * 16384, kW + i * 16384,
                                              vW + i * 16384, qb + i * 128, kb + i * 128,
                                              vb + i * 128, Qh, Ql, Kh, Kl, Vh, Vl);
    attn_mf2<<<dim3((NN + 63) / 64, ksplit, BB), blk, 0, stream>>>(
        Qh, Ql, Kh, Kl, Vh, Vl, srcp, tgtp, pacc, pm, pl, chunk);
    attn_combine<<<(FEAT + 255) / 256, blk, 0, stream>>>(pacc, pm, pl, MSG, ksplit);
    conv_k<128, 64, 0, 1, 1><<<dim3(PT, 1), blk, 0, stream>>>(
        MSG, T1, m1W + i * 8192, m1b + i * 64, nullptr);
    bn_stats<64><<<64, blk, 0, stream>>>(T1, m1g + i * 64, m1beta + i * 64, SS);
    bn_apply<64><<<G_HALF, blk, 0, stream>>>(T1, SS, T1);
    conv_k<64, 64, 0, 0, 1><<<dim3(PT, 1), blk, 0, stream>>>(
        T1, T2, m2W + i * 4096, m2b + i * 64, nullptr);
    bn_stats<64><<<64, blk, 0, stream>>>(T2, m2g + i * 64, m2beta + i * 64, SS);
    bn_apply<64><<<G_HALF, blk, 0, stream>>>(T2, SS, T2);
    conv_k<64, 128, 2, 0, 2><<<dim3(PT, 2), blk, 0, stream>>>(
        T2, X, m3W + i * 8192, m3b + i * 128, X);
  }

  conv_k<128, 32, 1, 0, 1><<<dim3(PT, 1), blk, 0, stream>>>(X, T1, c1W, c1b, nullptr);
  conv_k<32, 32, 1, 0, 1><<<dim3(PT, 1), blk, 0, stream>>>(T1, T2, c2W, c2b, nullptr);
  head_c3<<<G_PTS, blk, 0, stream>>>(T2, c3W, c3b, (float*)d_out);
  norm_out<<<G_PTS, blk, 0, stream>>>(X, (float*)d_out);
}

// Round 8
// 1680.973 us; speedup vs baseline: 4.0783x; 1.1564x over previous
//
#include <hip/hip_runtime.h>
#include <hip/hip_bf16.h>

// PointDSC-like network. B=2, N=3000, C=128, H=1, L=6. FP32 I/O.
// Round 8: attention with in-register softmax (no Sg LDS, shuffle reductions,
// 8 expf/lane/tile), P->LDS->A-fragment barrier kept (round-7 proven fix).
// LDS 53.2->43.9 KB (3 blocks/CU). BN+relu for T1/T2 fused into consumer convs.

#define BB 2
#define NN 3000
#define CC 128
#define LAYERS 6
#define BN_EPS 1e-5f
#define ATT_SCALE 0.08838834764831845f  // 1/sqrt(128)

typedef _Float16 f16;
typedef _Float16 f16x8 __attribute__((ext_vector_type(8)));
typedef float f32x4 __attribute__((ext_vector_type(4)));

// ---------------- init embedding
__global__ void init_conv(const float* __restrict__ corr, const float* __restrict__ W,
                          const float* __restrict__ bias, float* __restrict__ x) {
  int idx = blockIdx.x * 256 + threadIdx.x;
  if (idx >= BB * CC * NN) return;
  int n = idx % NN;
  int c = (idx / NN) % CC;
  int b = idx / (NN * CC);
  const float* cp = corr + (b * NN + n) * 6;
  float acc = bias[c];
#pragma unroll
  for (int d = 0; d < 6; ++d) acc += W[c * 6 + d] * cp[d];
  x[idx] = acc;
}

// ---------------- generic pointwise conv (proven)
// BNIN: apply y = relu(x*bns[ci]+bns[CIN+ci]) while staging input.
template <int CIN, int COUT, int MODE, int INPT, int CSPLIT, int BNIN>
__launch_bounds__(256)
__global__ void conv_k(const float* __restrict__ in, float* __restrict__ out,
                       const float* __restrict__ W, const float* __restrict__ bias,
                       const float* __restrict__ res, const float* __restrict__ bns) {
  constexpr int COB = COUT / CSPLIT;
  constexpr int CH = (CIN > 64) ? 64 : CIN;
  constexpr int KPT = COB / 32;
  __shared__ alignas(16) float Xs[CIN][INPT ? 36 : 32];
  __shared__ float Ws[COB][CH + 1];
  const int tid = threadIdx.x;
  const int p0 = blockIdx.x * 32;
  const int co0 = blockIdx.y * COB;

  if (INPT == 0) {
    for (int idx = tid; idx < CIN * 32; idx += 256) {
      int ci = idx >> 5, j = idx & 31;
      int p = p0 + j;
      float v = 0.f;
      if (p < BB * NN) {
        int b = p / NN, n = p % NN;
        v = in[(b * CIN + ci) * NN + n];
        if (BNIN) {
          v = v * bns[ci] + bns[CIN + ci];
          v = v > 0.f ? v : 0.f;
        }
      }
      Xs[ci][j] = v;
    }
  } else {
    for (int idx = tid; idx < CIN * 32; idx += 256) {
      int j = idx / CIN, ci = idx % CIN;
      int p = p0 + j;
      float v = 0.f;
      if (p < BB * NN) {
        v = in[p * CIN + ci];
        if (BNIN) {
          v = v * bns[ci] + bns[CIN + ci];
          v = v > 0.f ? v : 0.f;
        }
      }
      Xs[ci][j] = v;
    }
  }

  const int nb = (tid % 8) * 4;
  const int cb = (tid / 8) * KPT;

  float acc[KPT][4];
#pragma unroll
  for (int k = 0; k < KPT; ++k)
#pragma unroll
    for (int j = 0; j < 4; ++j) acc[k][j] = 0.f;

  for (int c0 = 0; c0 < CIN; c0 += CH) {
    __syncthreads();
    for (int idx = tid; idx < COB * CH; idx += 256) {
      int co = idx / CH, cc = idx % CH;
      Ws[co][cc] = W[(co0 + co) * CIN + c0 + cc];
    }
    __syncthreads();
#pragma unroll 4
    for (int cc = 0; cc < CH; ++cc) {
      float4 xv = *reinterpret_cast<const float4*>(&Xs[c0 + cc][nb]);
#pragma unroll
      for (int k = 0; k < KPT; ++k) {
        float w = Ws[cb + k][cc];
        acc[k][0] += w * xv.x;
        acc[k][1] += w * xv.y;
        acc[k][2] += w * xv.z;
        acc[k][3] += w * xv.w;
      }
    }
  }

#pragma unroll
  for (int k = 0; k < KPT; ++k) {
    float bv = bias[co0 + cb + k];
#pragma unroll
    for (int j = 0; j < 4; ++j) {
      int p = p0 + nb + j;
      if (p < BB * NN) {
        int b = p / NN, n = p % NN;
        int o = (b * COUT + co0 + cb + k) * NN + n;
        float v = acc[k][j] + bv;
        if (MODE == 1) v = v > 0.f ? v : 0.f;
        if (MODE == 2) v += res[o];
        out[o] = v;
      }
    }
  }
}

// ---------------- fused QKV conv -> hi/lo f16 planes (proven)
__launch_bounds__(256)
__global__ void conv_qkv(const float* __restrict__ X,
                         const float* __restrict__ qW, const float* __restrict__ kW,
                         const float* __restrict__ vW, const float* __restrict__ qb,
                         const float* __restrict__ kb, const float* __restrict__ vb,
                         f16* __restrict__ Qh, f16* __restrict__ Ql,
                         f16* __restrict__ Kh, f16* __restrict__ Kl,
                         f16* __restrict__ Vh, f16* __restrict__ Vl) {
  __shared__ alignas(16) float Xs[128][32];
  __shared__ float Ws[64][65];
  const int tid = threadIdx.x;
  const int p0 = blockIdx.x * 32;
  const int sel = blockIdx.y >> 1;
  const int co0 = (blockIdx.y & 1) * 64;
  const float* W = (sel == 0) ? qW : (sel == 1) ? kW : vW;
  const float* bias = (sel == 0) ? qb : (sel == 1) ? kb : vb;

  for (int idx = tid; idx < 128 * 32; idx += 256) {
    int ci = idx >> 5, j = idx & 31;
    int p = p0 + j;
    float v = 0.f;
    if (p < BB * NN) {
      int b = p / NN, n = p % NN;
      v = X[(b * 128 + ci) * NN + n];
    }
    Xs[ci][j] = v;
  }

  const int nb = (tid % 8) * 4;
  const int cb = (tid / 8) * 2;
  float acc[2][4] = {{0.f, 0.f, 0.f, 0.f}, {0.f, 0.f, 0.f, 0.f}};

  for (int c0 = 0; c0 < 128; c0 += 64) {
    __syncthreads();
    for (int idx = tid; idx < 64 * 64; idx += 256) {
      int co = idx >> 6, cc = idx & 63;
      Ws[co][cc] = W[(co0 + co) * 128 + c0 + cc];
    }
    __syncthreads();
#pragma unroll 4
    for (int cc = 0; cc < 64; ++cc) {
      float4 xv = *reinterpret_cast<const float4*>(&Xs[c0 + cc][nb]);
#pragma unroll
      for (int k = 0; k < 2; ++k) {
        float w = Ws[cb + k][cc];
        acc[k][0] += w * xv.x;
        acc[k][1] += w * xv.y;
        acc[k][2] += w * xv.z;
        acc[k][3] += w * xv.w;
      }
    }
  }

#pragma unroll
  for (int k = 0; k < 2; ++k) {
    int co = co0 + cb + k;
    float bv = bias[co];
#pragma unroll
    for (int j = 0; j < 4; ++j) {
      int p = p0 + nb + j;
      if (p < BB * NN) {
        int b = p / NN, n = p % NN;
        float v = acc[k][j] + bv;
        f16 h = (f16)v;
        f16 lo = (f16)(v - (float)h);
        if (sel == 0) {
          size_t o = (size_t)(b * NN + n) * CC + co;
          Qh[o] = h; Ql[o] = lo;
        } else if (sel == 1) {
          size_t o = (size_t)(b * NN + n) * CC + co;
          Kh[o] = h; Kl[o] = lo;
        } else {
          size_t o = (size_t)(b * CC + co) * NN + n;
          Vh[o] = h; Vl[o] = lo;
        }
      }
    }
  }
}

// ---------------- BN (proven)
template <int COUT>
__launch_bounds__(256)
__global__ void bn_stats(const float* __restrict__ y, const float* __restrict__ g,
                         const float* __restrict__ beta, float* __restrict__ ss) {
  int c = blockIdx.x;
  float s = 0.f, s2 = 0.f;
  for (int b = 0; b < BB; ++b) {
    const float* row = y + (b * COUT + c) * NN;
    for (int n = threadIdx.x; n < NN; n += 256) {
      float v = row[n];
      s += v;
      s2 += v * v;
    }
  }
  for (int off = 32; off > 0; off >>= 1) {
    s += __shfl_down(s, off);
    s2 += __shfl_down(s2, off);
  }
  __shared__ float rs[4], rs2[4];
  int wid = threadIdx.x >> 6, lane = threadIdx.x & 63;
  if (lane == 0) {
    rs[wid] = s;
    rs2[wid] = s2;
  }
  __syncthreads();
  if (threadIdx.x == 0) {
    float S = 0.f, S2 = 0.f;
    for (int w = 0; w < 4; ++w) {
      S += rs[w];
      S2 += rs2[w];
    }
    const float inv_cnt = 1.f / (float)(BB * NN);
    float mean = S * inv_cnt;
    float var = S2 * inv_cnt - mean * mean;
    float scale = g[c] * rsqrtf(var + BN_EPS);
    ss[c] = scale;
    ss[COUT + c] = beta[c] - mean * scale;
  }
}

template <int COUT>
__global__ void bn_apply(const float* __restrict__ y, const float* __restrict__ ss,
                         float* __restrict__ out) {
  int idx = blockIdx.x * 256 + threadIdx.x;
  if (idx >= BB * COUT * NN) return;
  int c = (idx / NN) % COUT;
  float v = y[idx] * ss[c] + ss[COUT + c];
  out[idx] = v > 0.f ? v : 0.f;
}

// ---------------- full-MFMA attention, in-register softmax.
// Block: 64 queries (4 waves x 16 rows), 32-key tiles over its K-chunk.
__launch_bounds__(256)
__global__ void attn_mf3(const f16* __restrict__ Qhp, const f16* __restrict__ Qlp,
                         const f16* __restrict__ Khp, const f16* __restrict__ Klp,
                         const f16* __restrict__ Vhp, const f16* __restrict__ Vlp,
                         const float* __restrict__ srcp, const float* __restrict__ tgtp,
                         float* __restrict__ pacc, float* __restrict__ pm,
                         float* __restrict__ pl, int chunk) {
  const int b = blockIdx.z;
  const int q0 = blockIdx.x * 64;
  const int s = blockIdx.y;
  const int cs = s * chunk;
  const int ce = min(cs + chunk, NN);
  const int tid = threadIdx.x;
  const int w = tid >> 6, lane = tid & 63, quad = lane >> 4, l15 = lane & 15;

  __shared__ f16 Ksh[32][136], Ksl[32][136];  // [key][chan] hi/lo (score MFMA B)
  __shared__ f16 Vsh[128][40], Vsl[128][40];  // [chan][key] hi/lo (PV MFMA B)
  __shared__ f16 Ps[4][16][40];               // per-wave P [qrow][key] (PV MFMA A)
  __shared__ float kps[6][36];                // key positions

  // q positions for D-mapping rows (row = quad*4+r) of this wave
  float qp[4][6];
  const int orow = q0 + w * 16;
#pragma unroll
  for (int r = 0; r < 4; ++r) {
    int o = orow + quad * 4 + r;
    if (o >= NN) o = NN - 1;
#pragma unroll
    for (int d = 0; d < 3; ++d) {
      qp[r][d] = srcp[(b * NN + o) * 3 + d];
      qp[r][3 + d] = tgtp[(b * NN + o) * 3 + d];
    }
  }
  // Q fragments hi/lo: A[m=l15][k=quad*8+j], chan = cc*32 + quad*8 + j
  f16x8 qh[4], ql[4];
  {
    int o = orow + l15;
    if (o >= NN) o = NN - 1;
    size_t base = (size_t)(b * NN + o) * CC + quad * 8;
#pragma unroll
    for (int cc = 0; cc < 4; ++cc) {
      qh[cc] = *reinterpret_cast<const f16x8*>(Qhp + base + cc * 32);
      ql[cc] = *reinterpret_cast<const f16x8*>(Qlp + base + cc * 32);
    }
  }

  float m[4], l[4];
#pragma unroll
  for (int r = 0; r < 4; ++r) {
    m[r] = -1e30f;
    l[r] = 0.f;
  }
  f32x4 acco[8];  // PV accumulator, rows quad*4+r, cols t*16+l15
#pragma unroll
  for (int t = 0; t < 8; ++t) acco[t] = (f32x4){0.f, 0.f, 0.f, 0.f};

  const int NT = (ce - cs + 31) >> 5;
  for (int it = 0; it < NT; ++it) {
    const int kk0 = cs + it * 32;
    __syncthreads();  // previous tile fully consumed (Ks/Vs/kps/Ps)
    // stage K hi/lo [32][128] f16
    for (int t = tid; t < 1024; t += 256) {
      int plane = t >> 9, row = (t >> 4) & 31, cu = t & 15;
      int kr = kk0 + row;
      if (kr >= NN) kr = NN - 1;
      const f16* src = (plane ? Klp : Khp) + (size_t)(b * NN + kr) * CC + cu * 8;
      uint4 v = *reinterpret_cast<const uint4*>(src);
      f16* dst = plane ? &Ksl[row][cu * 8] : &Ksh[row][cu * 8];
      *reinterpret_cast<uint4*>(dst) = v;
    }
    // stage V hi/lo [128][32] f16 (clamped base; OOR keys get p=0 anyway)
    for (int t = tid; t < 1024; t += 256) {
      int plane = t >> 9, c = (t >> 2) & 127, iu = t & 3;
      int kb = kk0 + iu * 8;
      if (kb > NN - 8) kb = NN - 8;
      const f16* src = (plane ? Vlp : Vhp) + (size_t)(b * CC + c) * NN + kb;
      uint4 v = *reinterpret_cast<const uint4*>(src);
      f16* dst = plane ? &Vsl[c][iu * 8] : &Vsh[c][iu * 8];
      *reinterpret_cast<uint4*>(dst) = v;
    }
    // stage key positions (clamped)
    for (int t = tid; t < 192; t += 256) {
      int d = t >> 5, i = t & 31;
      int ig = kk0 + i;
      if (ig >= NN) ig = NN - 1;
      kps[d][i] = (d < 3) ? srcp[(b * NN + ig) * 3 + d] : tgtp[(b * NN + ig) * 3 + d - 3];
    }
    __syncthreads();

    // ---- MFMA scores: 3-term hi/lo QK^T -> 16x32 per wave
    f32x4 accs[2];
#pragma unroll
    for (int k4 = 0; k4 < 2; ++k4) accs[k4] = (f32x4){0.f, 0.f, 0.f, 0.f};
#pragma unroll
    for (int cc = 0; cc < 4; ++cc) {
#pragma unroll
      for (int k4 = 0; k4 < 2; ++k4) {
        f16x8 bh = *reinterpret_cast<const f16x8*>(&Ksh[k4 * 16 + l15][cc * 32 + quad * 8]);
        f16x8 bl = *reinterpret_cast<const f16x8*>(&Ksl[k4 * 16 + l15][cc * 32 + quad * 8]);
        accs[k4] = __builtin_amdgcn_mfma_f32_16x16x32_f16(qh[cc], bl, accs[k4], 0, 0, 0);
        accs[k4] = __builtin_amdgcn_mfma_f32_16x16x32_f16(ql[cc], bh, accs[k4], 0, 0, 0);
        accs[k4] = __builtin_amdgcn_mfma_f32_16x16x32_f16(qh[cc], bh, accs[k4], 0, 0, 0);
      }
    }

    // ---- sc gate + mask in registers (D-mapping: col=l15 key, row=quad*4+r query)
    float sv[2][4];
#pragma unroll
    for (int k4 = 0; k4 < 2; ++k4) {
      int iloc = k4 * 16 + l15;
      int ig = kk0 + iloc;
      float kx = kps[0][iloc], ky = kps[1][iloc], kz = kps[2][iloc];
      float tx = kps[3][iloc], ty = kps[4][iloc], tz = kps[5][iloc];
#pragma unroll
      for (int r = 0; r < 4; ++r) {
        float dx = qp[r][0] - kx, dy = qp[r][1] - ky, dz = qp[r][2] - kz;
        float dsrc = sqrtf(dx * dx + dy * dy + dz * dz);
        float ex = qp[r][3] - tx, ey = qp[r][4] - ty, ez = qp[r][5] - tz;
        float dtgt = sqrtf(ex * ex + ey * ey + ez * ez);
        float diff = dsrc - dtgt;
        float gg = 1.f - diff * diff;
        gg = gg > 0.f ? gg : 0.f;
        float val = accs[k4][r] * (ATT_SCALE * gg);
        sv[k4][r] = (ig < ce) ? val : -1e30f;
      }
    }

    // ---- in-register online softmax: row reductions over 16 l15 lanes
    float tmax[4];
#pragma unroll
    for (int r = 0; r < 4; ++r) tmax[r] = fmaxf(sv[0][r], sv[1][r]);
#pragma unroll
    for (int d = 1; d <= 8; d <<= 1)
#pragma unroll
      for (int r = 0; r < 4; ++r) tmax[r] = fmaxf(tmax[r], __shfl_xor(tmax[r], d));

    float alpha[4], ps[4];
    f16 pf[2][4];
#pragma unroll
    for (int r = 0; r < 4; ++r) {
      float mn = fmaxf(m[r], tmax[r]);
      alpha[r] = __expf(m[r] - mn);
      m[r] = mn;
      pf[0][r] = (f16)__expf(sv[0][r] - mn);
      pf[1][r] = (f16)__expf(sv[1][r] - mn);
      ps[r] = (float)pf[0][r] + (float)pf[1][r];  // rounded: num/denom consistent
    }
#pragma unroll
    for (int d = 1; d <= 8; d <<= 1)
#pragma unroll
      for (int r = 0; r < 4; ++r) ps[r] += __shfl_xor(ps[r], d);
#pragma unroll
    for (int r = 0; r < 4; ++r) {
      l[r] = l[r] * alpha[r] + ps[r];
#pragma unroll
      for (int t = 0; t < 8; ++t) acco[t][r] *= alpha[r];
    }
    // write P tile (wave-private, read cross-lane after barrier)
#pragma unroll
    for (int r = 0; r < 4; ++r) {
      Ps[w][quad * 4 + r][l15] = pf[0][r];
      Ps[w][quad * 4 + r][16 + l15] = pf[1][r];
    }
    __syncthreads();  // Ps writes complete before cross-lane A-fragment reads

    // ---- MFMA PV: A = Ps[m=l15][k=quad*8+j], B = V hi/lo (16 MFMAs)
    {
      f16x8 af = *reinterpret_cast<const f16x8*>(&Ps[w][l15][quad * 8]);
#pragma unroll
      for (int t = 0; t < 8; ++t) {
        f16x8 vh = *reinterpret_cast<const f16x8*>(&Vsh[t * 16 + l15][quad * 8]);
        f16x8 vl = *reinterpret_cast<const f16x8*>(&Vsl[t * 16 + l15][quad * 8]);
        acco[t] = __builtin_amdgcn_mfma_f32_16x16x32_f16(af, vl, acco[t], 0, 0, 0);
        acco[t] = __builtin_amdgcn_mfma_f32_16x16x32_f16(af, vh, acco[t], 0, 0, 0);
      }
    }
  }

  // ---- write partials: rows quad*4+r (identical across l15 lanes -> l15==0 writes)
  const int pidx = s * BB + b;
  if (l15 == 0) {
#pragma unroll
    for (int r = 0; r < 4; ++r) {
      int o = orow + quad * 4 + r;
      if (o < NN) {
        pm[pidx * NN + o] = m[r];
        pl[pidx * NN + o] = l[r];
      }
    }
  }
#pragma unroll
  for (int r = 0; r < 4; ++r) {
    int o = orow + quad * 4 + r;
    if (o < NN) {
      size_t base2 = ((size_t)pidx * NN + o) * CC;
#pragma unroll
      for (int t = 0; t < 8; ++t) pacc[base2 + t * 16 + l15] = acco[t][r];
    }
  }
}

// ---------------- combine K-split partials -> msg fp32 [B,N,C]
__global__ void attn_combine(const float* __restrict__ pacc, const float* __restrict__ pm,
                             const float* __restrict__ pl, float* __restrict__ msg,
                             int ksplit) {
  int idx = blockIdx.x * 256 + threadIdx.x;
  if (idx >= BB * NN * CC) return;
  int c = idx & 127;
  int rem = idx >> 7;
  int o = rem % NN;
  int b = rem / NN;
  float M = -1e30f;
  for (int s = 0; s < ksplit; ++s) M = fmaxf(M, pm[(s * BB + b) * NN + o]);
  float L = 0.f, V = 0.f;
  for (int s = 0; s < ksplit; ++s) {
    int pi = s * BB + b;
    float e = __expf(pm[pi * NN + o] - M);
    L += pl[pi * NN + o] * e;
    V += pacc[((size_t)pi * NN + o) * CC + c] * e;
  }
  msg[idx] = V / L;
}

// ---------------- head + output
__global__ void head_c3(const float* __restrict__ h, const float* __restrict__ W,
                        const float* __restrict__ bias, float* __restrict__ out) {
  int p = blockIdx.x * 256 + threadIdx.x;
  if (p >= BB * NN) return;
  int b = p / NN, n = p % NN;
  float acc = bias[0];
#pragma unroll
  for (int k = 0; k < 32; ++k) acc += W[k] * h[(b * 32 + k) * NN + n];
  out[p] = acc;
}

__global__ void norm_out(const float* __restrict__ x, float* __restrict__ out) {
  int p = blockIdx.x * 256 + threadIdx.x;
  if (p >= BB * NN) return;
  int b = p / NN, n = p % NN;
  float ss = 0.f;
  for (int c = 0; c < CC; ++c) {
    float v = x[(b * CC + c) * NN + n];
    ss += v * v;
  }
  float nrm = sqrtf(ss);
  nrm = nrm > 1e-12f ? nrm : 1e-12f;
  float inv = 1.f / nrm;
  for (int c = 0; c < CC; ++c) {
    float v = x[(b * CC + c) * NN + n];
    out[BB * NN + (b * CC + c) * NN + n] = v * inv;
  }
}

extern "C" void kernel_launch(void* const* d_in, const int* in_sizes, int n_in,
                              void* d_out, int out_size, void* d_ws, size_t ws_size,
                              hipStream_t stream) {
  const float* corr = (const float*)d_in[0];
  const float* srcp = (const float*)d_in[1];
  const float* tgtp = (const float*)d_in[2];
  const float* initW = (const float*)d_in[3];
  const float* initb = (const float*)d_in[4];
  const float* pcnW = (const float*)d_in[5];
  const float* pcnb = (const float*)d_in[6];
  const float* pcng = (const float*)d_in[7];
  const float* pcnbeta = (const float*)d_in[8];
  const float* qW = (const float*)d_in[9];
  const float* qb = (const float*)d_in[10];
  const float* kW = (const float*)d_in[11];
  const float* kb = (const float*)d_in[12];
  const float* vW = (const float*)d_in[13];
  const float* vb = (const float*)d_in[14];
  const float* m1W = (const float*)d_in[15];
  const float* m1b = (const float*)d_in[16];
  const float* m1g = (const float*)d_in[17];
  const float* m1beta = (const float*)d_in[18];
  const float* m2W = (const float*)d_in[19];
  const float* m2b = (const float*)d_in[20];
  const float* m2g = (const float*)d_in[21];
  const float* m2beta = (const float*)d_in[22];
  const float* m3W = (const float*)d_in[23];
  const float* m3b = (const float*)d_in[24];
  const float* c1W = (const float*)d_in[25];
  const float* c1b = (const float*)d_in[26];
  const float* c2W = (const float*)d_in[27];
  const float* c2b = (const float*)d_in[28];
  const float* c3W = (const float*)d_in[29];
  const float* c3b = (const float*)d_in[30];

  const int FEAT = BB * CC * NN;   // 768000
  const int PLANE = FEAT / 2;      // one f16 plane in float units (384000)
  float* ws = (float*)d_ws;
  float* X = ws;
  float* Y = X + FEAT;
  float* QhF = Y + FEAT;
  float* QlF = QhF + PLANE;
  float* KhF = QlF + PLANE;
  float* KlF = KhF + PLANE;
  float* VhF = KlF + PLANE;
  float* VlF = VhF + PLANE;
  float* SS = VlF + PLANE;
  float* pacc = SS + 256;
  f16* Qh = (f16*)QhF;
  f16* Ql = (f16*)QlF;
  f16* Kh = (f16*)KhF;
  f16* Kl = (f16*)KlF;
  f16* Vh = (f16*)VhF;
  f16* Vl = (f16*)VlF;
  float* MSG = Y;
  float* T1 = QhF;
  float* T2 = KhF;

  const size_t base_f = (size_t)(2 * FEAT + 6 * PLANE + 256);
  const size_t per_f = (size_t)BB * NN * CC + 2 * (size_t)BB * NN;
  int ksplit = 8;
  while (ksplit > 1 && (base_f + (size_t)ksplit * per_f) * 4 > ws_size) ksplit >>= 1;
  const int chunk = (((NN + ksplit - 1) / ksplit) + 7) & ~7;
  float* pm = pacc + (size_t)ksplit * BB * NN * CC;
  float* pl = pm + (size_t)ksplit * BB * NN;

  dim3 blk(256);
  const int PT = (BB * NN + 31) / 32;  // 188
  const int G_FEAT = (FEAT + 255) / 256;
  const int G_PTS = (BB * NN + 255) / 256;

  init_conv<<<G_FEAT, blk, 0, stream>>>(corr, initW, initb, X);

  for (int i = 0; i < LAYERS; ++i) {
    conv_k<128, 128, 0, 0, 2, 0><<<dim3(PT, 2), blk, 0, stream>>>(
        X, Y, pcnW + i * 16384, pcnb + i * 128, nullptr, nullptr);
    bn_stats<128><<<128, blk, 0, stream>>>(Y, pcng + i * 128, pcnbeta + i * 128, SS);
    bn_apply<128><<<G_FEAT, blk, 0, stream>>>(Y, SS, X);
    conv_qkv<<<dim3(PT, 6), blk, 0, stream>>>(X, qW + i * 16384, kW + i * 16384,
                                              vW + i * 16384, qb + i * 128, kb + i * 128,
                                              vb + i * 128, Qh, Ql, Kh, Kl, Vh, Vl);
    attn_mf3<<<dim3((NN + 63) / 64, ksplit, BB), blk, 0, stream>>>(
        Qh, Ql, Kh, Kl, Vh, Vl, srcp, tgtp, pacc, pm, pl, chunk);
    attn_combine<<<(FEAT + 255) / 256, blk, 0, stream>>>(pacc, pm, pl, MSG, ksplit);
    // bottleneck MLP: bn+relu of T1/T2 fused into consumer conv staging
    conv_k<128, 64, 0, 1, 1, 0><<<dim3(PT, 1), blk, 0, stream>>>(
        MSG, T1, m1W + i * 8192, m1b + i * 64, nullptr, nullptr);
    bn_stats<64><<<64, blk, 0, stream>>>(T1, m1g + i * 64, m1beta + i * 64, SS);
    conv_k<64, 64, 0, 0, 1, 1><<<dim3(PT, 1), blk, 0, stream>>>(
        T1, T2, m2W + i * 4096, m2b + i * 64, nullptr, SS);
    bn_stats<64><<<64, blk, 0, stream>>>(T2, m2g + i * 64, m2beta + i * 64, SS);
    conv_k<64, 128, 2, 0, 2, 1><<<dim3(PT, 2), blk, 0, stream>>>(
        T2, X, m3W + i * 8192, m3b + i * 128, X, SS);
  }

  conv_k<128, 32, 1, 0, 1, 0><<<dim3(PT, 1), blk, 0, stream>>>(X, T1, c1W, c1b, nullptr, nullptr);
  conv_k<32, 32, 1, 0, 1, 0><<<dim3(PT, 1), blk, 0, stream>>>(T1, T2, c2W, c2b, nullptr, nullptr);
  head_c3<<<G_PTS, blk, 0, stream>>>(T2, c3W, c3b, (float*)d_out);
  norm_out<<<G_PTS, blk, 0, stream>>>(X, (float*)d_out);
}